// Round 9
// baseline (3102.712 us; speedup 1.0000x reference)
//
#include <hip/hip_runtime.h>

typedef __attribute__((ext_vector_type(8))) short bf16x8;
typedef __attribute__((ext_vector_type(4))) float f32x4;

#define T_LEN 256
// pack offsets (short units)
#define OFF_W1   0
#define OFF_W2   8192
#define OFF_W31  24576
#define OFF_W3   40960
#define OFF_WU1  49152
#define OFF_WR1  65536
#define OFF_WN1  81920
#define OFF_WU2  98304
#define OFF_WR2  106496
#define OFF_WN2  114688
#define OFF_B3W1 131072   // f32[128] appended after bf16 packs
#define PREP_TOT 131200

// LDS layout (short units). Two activation halves + ONE shared weight stage.
// per-half (base HBASE = half*8192):
#define HA_O   0      // [16][128]; also r-gate f32 overlay (g2..g3)
#define HB_O   2048   // [16][128]; first 1024 shorts double as st-mean
#define SGH_O  4096   // [16][128]
#define SGL_O  6144   // [16][128]; also u-gate f32 overlay (g2..g5)
// shared weight stage = pack[40960..98304):
#define WS_O   16384
#define W3S    16384  // 16 blocks  (8192 shorts)
#define WU1S   24576  // 32 blocks  (16384)
#define WR1S   40960  // 32 blocks  (16384)
#define WN1S   57344  // 32 blocks  (16384) -> ends 73728
#define LDS_SHORTS 73728
#define WS_COPY 7168  // 57344/8 b128 copies

__device__ __forceinline__ unsigned short bf16r(float f){
  unsigned int x = __builtin_bit_cast(unsigned int, f);
  unsigned int r = (x + 0x7FFFu + ((x >> 16) & 1u)) >> 16;
  return (unsigned short)r;
}
__device__ __forceinline__ float bf16tof(unsigned short u){
  unsigned int v = ((unsigned int)u) << 16;
  return __builtin_bit_cast(float, v);
}
__device__ __forceinline__ float fast_tanh(float x){
  float e = __builtin_amdgcn_exp2f(x * 2.885390081777927f);   // exp(2x)
  return 1.0f - 2.0f * __builtin_amdgcn_rcpf(1.0f + e);
}
__device__ __forceinline__ float fast_sigmoid(float x){
  float e = __builtin_amdgcn_exp2f(x * -1.4426950408889634f); // exp(-x)
  return __builtin_amdgcn_rcpf(1.0f + e);
}
__device__ __forceinline__ f32x4 mfma16(bf16x8 a, bf16x8 b, f32x4 c){
  return __builtin_amdgcn_mfma_f32_16x16x32_bf16(a, b, c, 0, 0, 0);
}
__device__ __forceinline__ bf16x8 load_bfrag(const unsigned short* p, int blk, int lane){
  return *reinterpret_cast<const bf16x8*>(p + ((blk << 6) + lane) * 8);
}
__device__ __forceinline__ bf16x8 ldsA(const unsigned short* LDSU, int idx){
  return *reinterpret_cast<const bf16x8*>(LDSU + idx);
}

// Pack weights to bf16 MFMA B-fragment order; compute W31=W3@W1, b3W1=b3@W1.
__global__ void prep_pack(const float* __restrict__ W1, const float* __restrict__ W2,
                          const float* __restrict__ W3, const float* __restrict__ Wu1,
                          const float* __restrict__ Wr1, const float* __restrict__ Wn1,
                          const float* __restrict__ Wu2, const float* __restrict__ Wr2,
                          const float* __restrict__ Wn2, const float* __restrict__ b3,
                          unsigned short* __restrict__ pack)
{
  int e = blockIdx.x * blockDim.x + threadIdx.x;
  if (e >= PREP_TOT) return;
  if (e >= OFF_B3W1){
    int j = e - OFF_B3W1;           // 0..127
    float s = 0.0f;
    for (int mm = 0; mm < 64; ++mm) s += b3[mm] * W1[mm * 128 + j];
    ((float*)(pack + OFF_B3W1))[j] = s;
    return;
  }
  const int offs[11] = {0, 8192, 24576, 40960, 49152, 65536, 81920, 98304, 106496, 114688, 131072};
  const int Ks[10] = {64,128,128,128,128,128,128,128,128,128};
  const int Ns[10] = {128,128,128,64,128,128,128,64,64,128};
  int m = 0;
  while (e >= offs[m + 1]) ++m;
  int el = e - offs[m];
  int j = el & 7, lane = (el >> 3) & 63, blk = el >> 9;
  int ksteps = Ks[m] >> 5;
  int ks = blk % ksteps, nt = blk / ksteps;
  int k = ks * 32 + ((lane >> 4) << 3) + j;
  int n = nt * 16 + (lane & 15);
  float v;
  if (m == 2){ // W31[k][n] = sum_mm W3[k][mm] * W1[mm][n]
    float s = 0.0f;
    for (int mm = 0; mm < 64; ++mm) s += W3[k * 64 + mm] * W1[mm * 128 + n];
    v = s;
  } else {
    const float* srcs[10] = {W1, W2, nullptr, W3, Wu1, Wr1, Wn1, Wu2, Wr2, Wn2};
    v = srcs[m][k * Ns[m] + n];
  }
  pack[e] = bf16r(v);
}

__global__ __launch_bounds__(1024, 4) void ode_rnn_main(
  const float* __restrict__ bts, const float* __restrict__ mtr,
  const float* __restrict__ b1, const float* __restrict__ b2, const float* __restrict__ b3,
  const float* __restrict__ bu1, const float* __restrict__ bu2,
  const float* __restrict__ br1, const float* __restrict__ br2,
  const float* __restrict__ bn1, const float* __restrict__ bn2,
  const float* __restrict__ Wu1f, const float* __restrict__ Wr1f, const float* __restrict__ Wn1f,
  const unsigned short* __restrict__ pack, float* __restrict__ out)
{
  __shared__ __align__(16) unsigned short LDSU[LDS_SHORTS];
  float* FUR = (float*)LDSU;
  const int tid = threadIdx.x;
  const int half = tid >> 9, tid5 = tid & 511;
  const int w = tid5 >> 6, lane = tid & 63;
  const int arow = lane & 15, g = lane >> 4, rb = g << 2;
  const int c128 = (w << 4) + arow;        // wave's 128-wide column (== state column)
  const int c64  = ((w & 3) << 4) + arow;  // wave's 64-wide column
  const bool isMean = (w < 4);
  const int rowBase = blockIdx.x * 32 + half * 16;
  const int HBASE = half << 13;            // 8192 shorts per activation half
  unsigned short* LB = LDSU + HBASE;
  // gate overlays (float units): FR over HA region, FU over SGL region
  const int FR_F = (half << 12) + 0;       // (HBASE + HA_O)/2
  const int FU_F = (half << 12) + 3072;    // (HBASE + SGL_O)/2

  // ---- prologue: stage shared weights into LDS (7168 b128 copies, 1024 thr) ----
#pragma unroll
  for (int i = 0; i < 7; ++i){
    int idx = tid + (i << 10);
    *reinterpret_cast<bf16x8*>(LDSU + WS_O + (idx << 3)) =
        *reinterpret_cast<const bf16x8*>(pack + OFF_W3 + (idx << 3));
  }
  // zero both halves' st buffers (1024 shorts each = 256 ull)
  if (tid < 512){
    int hf = tid >> 8, idx = tid & 255;
    ((unsigned long long*)(LDSU + (hf << 13) + HB_O))[idx] = 0ULL;
  }

  // precomputed LDS indices (short units, relative to LB)
  int a128[4], wr128[4], wr64[4], furi[4], a64v[2];
#pragma unroll
  for (int ks = 0; ks < 4; ++ks) a128[ks] = arow*128 + ((32*ks + 8*g) ^ (arow << 3));
#pragma unroll
  for (int ks = 0; ks < 2; ++ks) a64v[ks] = arow*64 + ((32*ks + 8*g) ^ ((arow & 7) << 3));
#pragma unroll
  for (int i = 0; i < 4; ++i){
    int r = rb + i;
    wr128[i] = r*128 + (c128 ^ (r << 3));
    wr64[i]  = r*64  + (c64 ^ ((r & 7) << 3));
    furi[i]  = r*64 + c64;
  }
  // staged-weight bases (absolute short units, + ks<<9 per k-step)
  const int wsb  = ((4*w) << 9) + (lane << 3);
  const int w3b  = W3S  + ((4*(w & 3)) << 9) + (lane << 3);
  const int wu1b = WU1S + wsb;
  const int wr1b = WR1S + wsb;
  const int wn1b = WN1S + wsb;

  // persistent per-wave weight fragments (registers)
  bf16x8 w1f[2], w2f[4], w31f[4], g2wf[4], n2f[4];
#pragma unroll
  for (int ks = 0; ks < 2; ++ks) w1f[ks]  = load_bfrag(pack + OFF_W1,  2*w + ks, lane);
#pragma unroll
  for (int ks = 0; ks < 4; ++ks){
    w2f[ks]  = load_bfrag(pack + OFF_W2,  4*w + ks, lane);
    w31f[ks] = load_bfrag(pack + OFF_W31, 4*w + ks, lane);
    g2wf[ks] = load_bfrag(pack + (isMean ? OFF_WU2 : OFF_WR2), 4*(w & 3) + ks, lane);
    n2f[ks]  = load_bfrag(pack + OFF_WN2, 4*w + ks, lane);
  }

  const float* b3w1p = (const float*)(pack + OFF_B3W1);
  const float b1c = b1[c128], b2c = b2[c128], b3c = b3[c64], b3w1c = b3w1p[c128];
  const float bu1c = bu1[c128], br1c = br1[c128], bn1c = bn1[c128], bn2c = bn2[c128];
  const float g2b = isMean ? bu2[c64] : br2[c64];
  const float wu1L = Wu1f[16384 + c128], wr1L = Wr1f[16384 + c128], wn1L = Wn1f[16384 + c128];

  __syncthreads();   // staging + st-zero visible

  f32x4 st = {0.f,0.f,0.f,0.f};   // w<4: mean state; w>=4: std state
  f32x4 yf = {0.f,0.f,0.f,0.f};   // mean_ode (mean waves)
  f32x4 u  = {0.f,0.f,0.f,0.f};

#pragma unroll 1
  for (int s = 0; s < T_LEN; ++s){
    const int tj = T_LEN - 1 - s;
    const float t1 = bts[2*tj];
    const float t0 = (s == 0) ? 5.0f : bts[2*tj + 2];
    const float hh = (t1 - t0);            // single RK4 step over the interval

    // prefetch x, mask early (d_in, cached); consumed many phases later
    f32x4 xr, mk;
#pragma unroll
    for (int i = 0; i < 4; ++i){
      int r = rowBase + rb + i;
      xr[i] = bts[(r * T_LEN + tj) * 2 + 1];
      mk[i] = mtr[r * T_LEN + tj];
    }

    f32x4 Hsum, R;

    // ---------------- RK4: one substep, 8 phases ----------------
    // p0: h1 stage1 from st-mean (K=64)
    {
      f32x4 acc = (f32x4){b1c, b1c, b1c, b1c};
      acc = mfma16(ldsA(LB, HB_O + a64v[0]), w1f[0], acc);
      acc = mfma16(ldsA(LB, HB_O + a64v[1]), w1f[1], acc);
      R = acc;
#pragma unroll
      for (int i = 0; i < 4; ++i) LB[HA_O + wr128[i]] = bf16r(fast_tanh(acc[i]));
    }
    __syncthreads();
    // 3x { h2 stage | h1 stage }
#pragma unroll
    for (int hs = 0; hs < 3; ++hs){
      const float wgt = (hs == 0) ? 1.0f : 2.0f;
      const float scn = (hs == 2) ? hh : 0.5f * hh;
      {
        f32x4 acc = (f32x4){b2c, b2c, b2c, b2c};
#pragma unroll
        for (int ks = 0; ks < 4; ++ks)
          acc = mfma16(ldsA(LB, HA_O + a128[ks]), w2f[ks], acc);
        f32x4 h;
#pragma unroll
        for (int i = 0; i < 4; ++i) h[i] = fast_tanh(acc[i]);
        if (hs == 0) Hsum = h;
        else {
#pragma unroll
          for (int i = 0; i < 4; ++i) Hsum[i] += wgt * h[i];
        }
#pragma unroll
        for (int i = 0; i < 4; ++i) LB[SGH_O + wr128[i]] = bf16r(h[i] * scn);
      }
      __syncthreads();
      {
        const float ac = (hs == 2) ? hh : 0.5f * hh;
        f32x4 acc2;
#pragma unroll
        for (int i = 0; i < 4; ++i) acc2[i] = R[i] + ac * b3w1c;
#pragma unroll
        for (int ks = 0; ks < 4; ++ks)
          acc2 = mfma16(ldsA(LB, SGH_O + a128[ks]), w31f[ks], acc2);
#pragma unroll
        for (int i = 0; i < 4; ++i) LB[HA_O + wr128[i]] = bf16r(fast_tanh(acc2[i]));
      }
      __syncthreads();
    }
    // p7: h2 stage 4, finalize Gsum hi/lo -> HB/SGH
    {
      f32x4 acc = (f32x4){b2c, b2c, b2c, b2c};
#pragma unroll
      for (int ks = 0; ks < 4; ++ks)
        acc = mfma16(ldsA(LB, HA_O + a128[ks]), w2f[ks], acc);
      const float sc6 = hh * (1.0f / 6.0f);
#pragma unroll
      for (int i = 0; i < 4; ++i){
        float h = fast_tanh(acc[i]);
        float gv = (Hsum[i] + h) * sc6;
        unsigned short hi = bf16r(gv);
        LB[HB_O  + wr128[i]] = hi;
        LB[SGH_O + wr128[i]] = bf16r(gv - bf16tof(hi));
      }
    }
    __syncthreads();
    // Y: recover mean_ode (W3 from LDS stage) + write state hi/lo -> HA/SGL
    if (isMean){
      f32x4 acc = {0.f,0.f,0.f,0.f};
#pragma unroll
      for (int ks = 0; ks < 4; ++ks)
        acc = mfma16(ldsA(LB, HB_O  + a128[ks]), ldsA(LDSU, w3b + (ks << 9)), acc);
#pragma unroll
      for (int ks = 0; ks < 4; ++ks)
        acc = mfma16(ldsA(LB, SGH_O + a128[ks]), ldsA(LDSU, w3b + (ks << 9)), acc);
#pragma unroll
      for (int i = 0; i < 4; ++i) yf[i] = st[i] + acc[i] + hh * b3c;
#pragma unroll
      for (int i = 0; i < 4; ++i){
        unsigned short hi = bf16r(yf[i]);
        LB[HA_O  + wr128[i]] = hi;
        LB[SGL_O + wr128[i]] = bf16r(yf[i] - bf16tof(hi));
      }
    } else {
#pragma unroll
      for (int i = 0; i < 4; ++i){
        unsigned short hi = bf16r(st[i]);
        LB[HA_O  + wr128[i]] = hi;
        LB[SGL_O + wr128[i]] = bf16r(st[i] - bf16tof(hi));
      }
    }
    __syncthreads();
    // g1: u & r first layers (weights from LDS stage; read HA/SGL, write HB/SGH)
    {
      f32x4 au = {0.f,0.f,0.f,0.f}, ar = {0.f,0.f,0.f,0.f};
#pragma unroll
      for (int ks = 0; ks < 4; ++ks){
        bf16x8 ah = ldsA(LB, HA_O  + a128[ks]);
        bf16x8 al = ldsA(LB, SGL_O + a128[ks]);
        bf16x8 bu = ldsA(LDSU, wu1b + (ks << 9));
        bf16x8 br_ = ldsA(LDSU, wr1b + (ks << 9));
        au = mfma16(al, bu, au);  au = mfma16(ah, bu, au);
        ar = mfma16(al, br_, ar); ar = mfma16(ah, br_, ar);
      }
#pragma unroll
      for (int i = 0; i < 4; ++i){
        au[i] = fast_tanh(au[i] + bu1c + xr[i] * wu1L);
        ar[i] = fast_tanh(ar[i] + br1c + xr[i] * wr1L);
      }
#pragma unroll
      for (int i = 0; i < 4; ++i){
        LB[HB_O  + wr128[i]] = bf16r(au[i]);
        LB[SGH_O + wr128[i]] = bf16r(ar[i]);
      }
    }
    __syncthreads();
    // g2: second layers from registers (mean->u from HB, std->r from SGH)
    // gate exchange: u -> FU (SGL overlay), r -> FR (HA overlay); both regions dead here
    f32x4 rr = {0.f,0.f,0.f,0.f};
    {
      f32x4 acc = {0.f,0.f,0.f,0.f};
      const int srcO = isMean ? HB_O : SGH_O;
#pragma unroll
      for (int ks = 0; ks < 4; ++ks)
        acc = mfma16(ldsA(LB, srcO + a128[ks]), g2wf[ks], acc);
      if (isMean){
#pragma unroll
        for (int i = 0; i < 4; ++i){ u[i] = fast_sigmoid(acc[i] + g2b); FUR[FU_F + furi[i]] = u[i]; }
      } else {
#pragma unroll
        for (int i = 0; i < 4; ++i){ rr[i] = fast_sigmoid(acc[i] + g2b); FUR[FR_F + furi[i]] = rr[i]; }
      }
    }
    __syncthreads();
    // g3: gated state yc -> HB(hi)/SGH(lo)
    {
      f32x4 yc;
      if (isMean){
#pragma unroll
        for (int i = 0; i < 4; ++i){ float r_ = FUR[FR_F + furi[i]]; yc[i] = yf[i] * r_; }
      } else {
#pragma unroll
        for (int i = 0; i < 4; ++i){ u[i] = FUR[FU_F + furi[i]]; yc[i] = st[i] * rr[i]; }
      }
#pragma unroll
      for (int i = 0; i < 4; ++i){
        unsigned short hi = bf16r(yc[i]);
        LB[HB_O  + wr128[i]] = hi;
        LB[SGH_O + wr128[i]] = bf16r(yc[i] - bf16tof(hi));
      }
    }
    __syncthreads();
    // g4: n first layer (weights from LDS stage; read HB/SGH, write HA)
    {
      f32x4 an = {0.f,0.f,0.f,0.f};
#pragma unroll
      for (int ks = 0; ks < 4; ++ks){
        bf16x8 ah = ldsA(LB, HB_O  + a128[ks]);
        bf16x8 al = ldsA(LB, SGH_O + a128[ks]);
        bf16x8 bn = ldsA(LDSU, wn1b + (ks << 9));
        an = mfma16(al, bn, an); an = mfma16(ah, bn, an);
      }
#pragma unroll
      for (int i = 0; i < 4; ++i) an[i] = fast_tanh(an[i] + bn1c + xr[i] * wn1L);
#pragma unroll
      for (int i = 0; i < 4; ++i) LB[HA_O + wr128[i]] = bf16r(an[i]);
    }
    __syncthreads();
    // g5: n second layer from registers + blend + write st-mean -> HB[16][64]
    {
      f32x4 ns = {0.f,0.f,0.f,0.f};
#pragma unroll
      for (int ks = 0; ks < 4; ++ks)
        ns = mfma16(ldsA(LB, HA_O + a128[ks]), n2f[ks], ns);
#pragma unroll
      for (int i = 0; i < 4; ++i){
        float nv = ns[i] + bn2c;
        float uu = u[i];
        float base = isMean ? yf[i] : st[i];
        float nm = (1.0f - uu) * nv + uu * base;
        float fs = mk[i] * nm + (1.0f - mk[i]) * base;
        st[i] = isMean ? fs : fabsf(fs);
      }
      if (isMean){
#pragma unroll
        for (int i = 0; i < 4; ++i) LB[HB_O + wr64[i]] = bf16r(st[i]);
      }
    }
    __syncthreads();
  }

  // ---------------- store ----------------
#pragma unroll
  for (int i = 0; i < 4; ++i){
    int r = rowBase + rb + i;
    if (isMean) out[r * 64 + c64] = st[i];
    else        out[524288 + r * 64 + c64] = st[i];
  }
}

extern "C" void kernel_launch(void* const* d_in, const int* in_sizes, int n_in,
                              void* d_out, int out_size, void* d_ws, size_t ws_size,
                              hipStream_t stream)
{
  (void)in_sizes; (void)n_in; (void)out_size; (void)ws_size;
  unsigned short* pack = (unsigned short*)d_ws;
  prep_pack<<<dim3((PREP_TOT + 255) / 256), dim3(256), 0, stream>>>(
      (const float*)d_in[2],  (const float*)d_in[4],  (const float*)d_in[6],
      (const float*)d_in[8],  (const float*)d_in[12], (const float*)d_in[16],
      (const float*)d_in[10], (const float*)d_in[14], (const float*)d_in[18],
      (const float*)d_in[7],  pack);
  ode_rnn_main<<<dim3(256), dim3(1024), 0, stream>>>(
      (const float*)d_in[0],  (const float*)d_in[1],
      (const float*)d_in[3],  (const float*)d_in[5],  (const float*)d_in[7],
      (const float*)d_in[9],  (const float*)d_in[11],
      (const float*)d_in[13], (const float*)d_in[15],
      (const float*)d_in[17], (const float*)d_in[19],
      (const float*)d_in[8],  (const float*)d_in[12], (const float*)d_in[16],
      (const unsigned short*)pack, (float*)d_out);
}

// Round 10
// 2051.767 us; speedup vs baseline: 1.5122x; 1.5122x over previous
//
#include <hip/hip_runtime.h>

typedef __attribute__((ext_vector_type(8))) short bf16x8;
typedef __attribute__((ext_vector_type(4))) float f32x4;

#define T_LEN 256
// pack offsets (short units)
#define OFF_W1   0
#define OFF_W2   8192
#define OFF_W31  24576
#define OFF_W3   40960
#define OFF_WU1  49152
#define OFF_WR1  65536
#define OFF_WN1  81920
#define OFF_WU2  98304
#define OFF_WR2  106496
#define OFF_WN2  114688
#define OFF_B3W1 131072   // f32[128] appended after bf16 packs
#define PREP_TOT 131200

// LDS layout (short units). Two activation halves (8192 shorts each) + ONE shared weight stage.
// per-half (base = half*8192):
#define HA_O   0      // [16][128]; also r-gate f32 overlay during g2..g3
#define HB_O   2048   // [16][128]; first 1024 shorts double as st-mean
#define SGH_O  4096   // [16][128]
#define SGL_O  6144   // [16][128]; also u-gate f32 overlay during g2..g3
// shared weight stage = pack[40960..98304):
#define WS_O   16384
#define W3S    16384  // 16 blocks  (8192 shorts)
#define WU1S   24576  // 32 blocks  (16384)
#define WR1S   40960  // 32 blocks  (16384)
#define WN1S   57344  // 32 blocks  (16384) -> ends 73728
#define LDS_SHORTS 73728
#define WS_COPY 7168  // 57344/8 b128 copies

__device__ __forceinline__ unsigned short bf16r(float f){
  unsigned int x = __builtin_bit_cast(unsigned int, f);
  unsigned int r = (x + 0x7FFFu + ((x >> 16) & 1u)) >> 16;
  return (unsigned short)r;
}
__device__ __forceinline__ float bf16tof(unsigned short u){
  unsigned int v = ((unsigned int)u) << 16;
  return __builtin_bit_cast(float, v);
}
__device__ __forceinline__ float fast_tanh(float x){
  float e = __builtin_amdgcn_exp2f(x * 2.885390081777927f);   // exp(2x)
  return 1.0f - 2.0f * __builtin_amdgcn_rcpf(1.0f + e);
}
__device__ __forceinline__ float fast_sigmoid(float x){
  float e = __builtin_amdgcn_exp2f(x * -1.4426950408889634f); // exp(-x)
  return __builtin_amdgcn_rcpf(1.0f + e);
}
__device__ __forceinline__ f32x4 mfma16(bf16x8 a, bf16x8 b, f32x4 c){
  return __builtin_amdgcn_mfma_f32_16x16x32_bf16(a, b, c, 0, 0, 0);
}
__device__ __forceinline__ bf16x8 load_bfrag(const unsigned short* p, int blk, int lane){
  return *reinterpret_cast<const bf16x8*>(p + ((blk << 6) + lane) * 8);
}
__device__ __forceinline__ bf16x8 ldsA(const unsigned short* LDSU, int idx){
  return *reinterpret_cast<const bf16x8*>(LDSU + idx);
}

// Pack weights to bf16 MFMA B-fragment order; compute W31=W3@W1, b3W1=b3@W1.
__global__ void prep_pack(const float* __restrict__ W1, const float* __restrict__ W2,
                          const float* __restrict__ W3, const float* __restrict__ Wu1,
                          const float* __restrict__ Wr1, const float* __restrict__ Wn1,
                          const float* __restrict__ Wu2, const float* __restrict__ Wr2,
                          const float* __restrict__ Wn2, const float* __restrict__ b3,
                          unsigned short* __restrict__ pack)
{
  int e = blockIdx.x * blockDim.x + threadIdx.x;
  if (e >= PREP_TOT) return;
  if (e >= OFF_B3W1){
    int j = e - OFF_B3W1;           // 0..127
    float s = 0.0f;
    for (int mm = 0; mm < 64; ++mm) s += b3[mm] * W1[mm * 128 + j];
    ((float*)(pack + OFF_B3W1))[j] = s;
    return;
  }
  const int offs[11] = {0, 8192, 24576, 40960, 49152, 65536, 81920, 98304, 106496, 114688, 131072};
  const int Ks[10] = {64,128,128,128,128,128,128,128,128,128};
  const int Ns[10] = {128,128,128,64,128,128,128,64,64,128};
  int m = 0;
  while (e >= offs[m + 1]) ++m;
  int el = e - offs[m];
  int j = el & 7, lane = (el >> 3) & 63, blk = el >> 9;
  int ksteps = Ks[m] >> 5;
  int ks = blk % ksteps, nt = blk / ksteps;
  int k = ks * 32 + ((lane >> 4) << 3) + j;
  int n = nt * 16 + (lane & 15);
  float v;
  if (m == 2){ // W31[k][n] = sum_mm W3[k][mm] * W1[mm][n]
    float s = 0.0f;
    for (int mm = 0; mm < 64; ++mm) s += W3[k * 64 + mm] * W1[mm * 128 + n];
    v = s;
  } else {
    const float* srcs[10] = {W1, W2, nullptr, W3, Wu1, Wr1, Wn1, Wu2, Wr2, Wn2};
    v = srcs[m][k * Ns[m] + n];
  }
  pack[e] = bf16r(v);
}

__global__ __launch_bounds__(512, 2) void ode_rnn_main(
  const float* __restrict__ bts, const float* __restrict__ mtr,
  const float* __restrict__ b1, const float* __restrict__ b2, const float* __restrict__ b3,
  const float* __restrict__ bu1, const float* __restrict__ bu2,
  const float* __restrict__ br1, const float* __restrict__ br2,
  const float* __restrict__ bn1, const float* __restrict__ bn2,
  const float* __restrict__ Wu1f, const float* __restrict__ Wr1f, const float* __restrict__ Wn1f,
  const unsigned short* __restrict__ pack, float* __restrict__ out)
{
  __shared__ __align__(16) unsigned short LDSU[LDS_SHORTS];
  float* FUR = (float*)LDSU;
  const int tid = threadIdx.x, w = tid >> 6, lane = tid & 63;
  const int arow = lane & 15, g = lane >> 4, rb = g << 2;
  const int c128 = (w << 4) + arow;        // wave's 128-wide column (== state column)
  const int c64  = ((w & 3) << 4) + arow;  // wave's 64-wide column
  const bool isMean = (w < 4);
  const int rowBase = blockIdx.x * 32;     // 32 rows per WG (two 16-row halves)

  // ---- prologue: stage shared weights into LDS (7168 b128 copies, 512 thr) ----
#pragma unroll
  for (int i = 0; i < 14; ++i){
    int idx = tid + (i << 9);
    *reinterpret_cast<bf16x8*>(LDSU + WS_O + (idx << 3)) =
        *reinterpret_cast<const bf16x8*>(pack + OFF_W3 + (idx << 3));
  }
  // zero both halves' st buffers (2 x 1024 shorts = 512 ull total)
  {
    int hf = tid >> 8, idx = tid & 255;
    ((unsigned long long*)(LDSU + (hf << 13) + HB_O))[idx] = 0ULL;
  }

  // precomputed LDS indices (short units, relative to half base)
  int a128[4], wr128[4], wr64[4], furi[4], a64v[2];
#pragma unroll
  for (int ks = 0; ks < 4; ++ks) a128[ks] = arow*128 + ((32*ks + 8*g) ^ (arow << 3));
#pragma unroll
  for (int ks = 0; ks < 2; ++ks) a64v[ks] = arow*64 + ((32*ks + 8*g) ^ ((arow & 7) << 3));
#pragma unroll
  for (int i = 0; i < 4; ++i){
    int r = rb + i;
    wr128[i] = r*128 + (c128 ^ (r << 3));
    wr64[i]  = r*64  + (c64 ^ ((r & 7) << 3));
    furi[i]  = r*64 + c64;
  }
  // staged-weight bases (absolute short units, + ks<<9 per k-step)
  const int wsb  = ((4*w) << 9) + (lane << 3);
  const int w3b  = W3S  + ((4*(w & 3)) << 9) + (lane << 3);
  const int wu1b = WU1S + wsb;
  const int wr1b = WR1S + wsb;
  const int wn1b = WN1S + wsb;

  // persistent per-wave weight fragments (registers, ~72 VGPR)
  bf16x8 w1f[2], w2f[4], w31f[4], g2wf[4], n2f[4];
#pragma unroll
  for (int ks = 0; ks < 2; ++ks) w1f[ks]  = load_bfrag(pack + OFF_W1,  2*w + ks, lane);
#pragma unroll
  for (int ks = 0; ks < 4; ++ks){
    w2f[ks]  = load_bfrag(pack + OFF_W2,  4*w + ks, lane);
    w31f[ks] = load_bfrag(pack + OFF_W31, 4*w + ks, lane);
    g2wf[ks] = load_bfrag(pack + (isMean ? OFF_WU2 : OFF_WR2), 4*(w & 3) + ks, lane);
    n2f[ks]  = load_bfrag(pack + OFF_WN2, 4*w + ks, lane);
  }

  const float* b3w1p = (const float*)(pack + OFF_B3W1);
  const float b1c = b1[c128], b2c = b2[c128], b3c = b3[c64], b3w1c = b3w1p[c128];
  const float bu1c = bu1[c128], br1c = br1[c128], bn1c = bn1[c128], bn2c = bn2[c128];
  const float g2b = isMean ? bu2[c64] : br2[c64];
  const float wu1L = Wu1f[16384 + c128], wr1L = Wr1f[16384 + c128], wn1L = Wn1f[16384 + c128];

  __syncthreads();   // staging + st-zero visible

  f32x4 st2[2], yf2[2], u2[2];
#pragma unroll
  for (int hf = 0; hf < 2; ++hf){
    st2[hf] = (f32x4){0.f,0.f,0.f,0.f};
    yf2[hf] = (f32x4){0.f,0.f,0.f,0.f};
    u2[hf]  = (f32x4){0.f,0.f,0.f,0.f};
  }

#pragma unroll 1
  for (int s = 0; s < T_LEN; ++s){
    const int tj = T_LEN - 1 - s;
    const float t1 = bts[2*tj];
    const float t0 = (s == 0) ? 5.0f : bts[2*tj + 2];
    const float hh = (t1 - t0);            // single RK4 step over the interval

    // prefetch x, mask for both halves (d_in, cached); consumed phases later
    f32x4 xr2[2], mk2[2];
#pragma unroll
    for (int hf = 0; hf < 2; ++hf)
#pragma unroll
      for (int i = 0; i < 4; ++i){
        int r = rowBase + 16*hf + rb + i;
        xr2[hf][i] = bts[(r * T_LEN + tj) * 2 + 1];
        mk2[hf][i] = mtr[r * T_LEN + tj];
      }

    f32x4 R2[2], Hsum2[2];

    // ---------------- RK4: one substep, 8 phases, both halves per phase ----------------
    // p0: h1 stage1 from st-mean (K=64)
#pragma unroll
    for (int hf = 0; hf < 2; ++hf){
      unsigned short* LB = LDSU + (hf << 13);
      f32x4 acc = (f32x4){b1c, b1c, b1c, b1c};
      acc = mfma16(ldsA(LB, HB_O + a64v[0]), w1f[0], acc);
      acc = mfma16(ldsA(LB, HB_O + a64v[1]), w1f[1], acc);
      R2[hf] = acc;
#pragma unroll
      for (int i = 0; i < 4; ++i) LB[HA_O + wr128[i]] = bf16r(fast_tanh(acc[i]));
    }
    __syncthreads();
    // 3x { h2 stage | h1 stage }
#pragma unroll
    for (int hs = 0; hs < 3; ++hs){
      const float wgt = (hs == 0) ? 1.0f : 2.0f;
      const float scn = (hs == 2) ? hh : 0.5f * hh;
#pragma unroll
      for (int hf = 0; hf < 2; ++hf){
        unsigned short* LB = LDSU + (hf << 13);
        f32x4 acc = (f32x4){b2c, b2c, b2c, b2c};
#pragma unroll
        for (int ks = 0; ks < 4; ++ks)
          acc = mfma16(ldsA(LB, HA_O + a128[ks]), w2f[ks], acc);
        f32x4 h;
#pragma unroll
        for (int i = 0; i < 4; ++i) h[i] = fast_tanh(acc[i]);
        if (hs == 0) Hsum2[hf] = h;
        else {
#pragma unroll
          for (int i = 0; i < 4; ++i) Hsum2[hf][i] += wgt * h[i];
        }
#pragma unroll
        for (int i = 0; i < 4; ++i) LB[SGH_O + wr128[i]] = bf16r(h[i] * scn);
      }
      __syncthreads();
      const float ac = (hs == 2) ? hh : 0.5f * hh;
#pragma unroll
      for (int hf = 0; hf < 2; ++hf){
        unsigned short* LB = LDSU + (hf << 13);
        f32x4 acc2;
#pragma unroll
        for (int i = 0; i < 4; ++i) acc2[i] = R2[hf][i] + ac * b3w1c;
#pragma unroll
        for (int ks = 0; ks < 4; ++ks)
          acc2 = mfma16(ldsA(LB, SGH_O + a128[ks]), w31f[ks], acc2);
#pragma unroll
        for (int i = 0; i < 4; ++i) LB[HA_O + wr128[i]] = bf16r(fast_tanh(acc2[i]));
      }
      __syncthreads();
    }
    // p7: h2 stage 4, finalize Gsum hi/lo -> HB/SGH
#pragma unroll
    for (int hf = 0; hf < 2; ++hf){
      unsigned short* LB = LDSU + (hf << 13);
      f32x4 acc = (f32x4){b2c, b2c, b2c, b2c};
#pragma unroll
      for (int ks = 0; ks < 4; ++ks)
        acc = mfma16(ldsA(LB, HA_O + a128[ks]), w2f[ks], acc);
      const float sc6 = hh * (1.0f / 6.0f);
#pragma unroll
      for (int i = 0; i < 4; ++i){
        float h = fast_tanh(acc[i]);
        float gv = (Hsum2[hf][i] + h) * sc6;
        unsigned short hi = bf16r(gv);
        LB[HB_O  + wr128[i]] = hi;
        LB[SGH_O + wr128[i]] = bf16r(gv - bf16tof(hi));
      }
    }
    __syncthreads();
    // Y: recover mean_ode (W3 from LDS stage) + write state hi/lo -> HA/SGL
    if (isMean){
#pragma unroll
      for (int hf = 0; hf < 2; ++hf){
        unsigned short* LB = LDSU + (hf << 13);
        f32x4 acc = {0.f,0.f,0.f,0.f};
#pragma unroll
        for (int ks = 0; ks < 4; ++ks)
          acc = mfma16(ldsA(LB, HB_O  + a128[ks]), ldsA(LDSU, w3b + (ks << 9)), acc);
#pragma unroll
        for (int ks = 0; ks < 4; ++ks)
          acc = mfma16(ldsA(LB, SGH_O + a128[ks]), ldsA(LDSU, w3b + (ks << 9)), acc);
#pragma unroll
        for (int i = 0; i < 4; ++i) yf2[hf][i] = st2[hf][i] + acc[i] + hh * b3c;
#pragma unroll
        for (int i = 0; i < 4; ++i){
          unsigned short hi = bf16r(yf2[hf][i]);
          LB[HA_O  + wr128[i]] = hi;
          LB[SGL_O + wr128[i]] = bf16r(yf2[hf][i] - bf16tof(hi));
        }
      }
    } else {
#pragma unroll
      for (int hf = 0; hf < 2; ++hf){
        unsigned short* LB = LDSU + (hf << 13);
#pragma unroll
        for (int i = 0; i < 4; ++i){
          unsigned short hi = bf16r(st2[hf][i]);
          LB[HA_O  + wr128[i]] = hi;
          LB[SGL_O + wr128[i]] = bf16r(st2[hf][i] - bf16tof(hi));
        }
      }
    }
    __syncthreads();
    // g1: u & r first layers (weights from LDS stage; read HA/SGL, write HB/SGH)
#pragma unroll
    for (int hf = 0; hf < 2; ++hf){
      unsigned short* LB = LDSU + (hf << 13);
      f32x4 au = {0.f,0.f,0.f,0.f}, ar = {0.f,0.f,0.f,0.f};
#pragma unroll
      for (int ks = 0; ks < 4; ++ks){
        bf16x8 ah = ldsA(LB, HA_O  + a128[ks]);
        bf16x8 al = ldsA(LB, SGL_O + a128[ks]);
        bf16x8 bu = ldsA(LDSU, wu1b + (ks << 9));
        bf16x8 br_ = ldsA(LDSU, wr1b + (ks << 9));
        au = mfma16(al, bu, au);  au = mfma16(ah, bu, au);
        ar = mfma16(al, br_, ar); ar = mfma16(ah, br_, ar);
      }
#pragma unroll
      for (int i = 0; i < 4; ++i){
        au[i] = fast_tanh(au[i] + bu1c + xr2[hf][i] * wu1L);
        ar[i] = fast_tanh(ar[i] + br1c + xr2[hf][i] * wr1L);
      }
#pragma unroll
      for (int i = 0; i < 4; ++i){
        LB[HB_O  + wr128[i]] = bf16r(au[i]);
        LB[SGH_O + wr128[i]] = bf16r(ar[i]);
      }
    }
    __syncthreads();
    // g2: second layers from registers (mean->u from HB, std->r from SGH)
    // gate exchange via overlays: u -> FU (SGL region), r -> FR (HA region); both dead here
    f32x4 rr2[2];
#pragma unroll
    for (int hf = 0; hf < 2; ++hf){
      unsigned short* LB = LDSU + (hf << 13);
      const int FR_F = (hf << 12) + 0;
      const int FU_F = (hf << 12) + 3072;
      f32x4 acc = {0.f,0.f,0.f,0.f};
      const int srcO = isMean ? HB_O : SGH_O;
#pragma unroll
      for (int ks = 0; ks < 4; ++ks)
        acc = mfma16(ldsA(LB, srcO + a128[ks]), g2wf[ks], acc);
      if (isMean){
#pragma unroll
        for (int i = 0; i < 4; ++i){ u2[hf][i] = fast_sigmoid(acc[i] + g2b); FUR[FU_F + furi[i]] = u2[hf][i]; }
      } else {
#pragma unroll
        for (int i = 0; i < 4; ++i){ rr2[hf][i] = fast_sigmoid(acc[i] + g2b); FUR[FR_F + furi[i]] = rr2[hf][i]; }
      }
    }
    __syncthreads();
    // g3: gated state yc -> HB(hi)/SGH(lo)
#pragma unroll
    for (int hf = 0; hf < 2; ++hf){
      unsigned short* LB = LDSU + (hf << 13);
      const int FR_F = (hf << 12) + 0;
      const int FU_F = (hf << 12) + 3072;
      f32x4 yc;
      if (isMean){
#pragma unroll
        for (int i = 0; i < 4; ++i){ float r_ = FUR[FR_F + furi[i]]; yc[i] = yf2[hf][i] * r_; }
      } else {
#pragma unroll
        for (int i = 0; i < 4; ++i){ u2[hf][i] = FUR[FU_F + furi[i]]; yc[i] = st2[hf][i] * rr2[hf][i]; }
      }
#pragma unroll
      for (int i = 0; i < 4; ++i){
        unsigned short hi = bf16r(yc[i]);
        LB[HB_O  + wr128[i]] = hi;
        LB[SGH_O + wr128[i]] = bf16r(yc[i] - bf16tof(hi));
      }
    }
    __syncthreads();
    // g4: n first layer (weights from LDS stage; read HB/SGH, write HA)
#pragma unroll
    for (int hf = 0; hf < 2; ++hf){
      unsigned short* LB = LDSU + (hf << 13);
      f32x4 an = {0.f,0.f,0.f,0.f};
#pragma unroll
      for (int ks = 0; ks < 4; ++ks){
        bf16x8 ah = ldsA(LB, HB_O  + a128[ks]);
        bf16x8 al = ldsA(LB, SGH_O + a128[ks]);
        bf16x8 bn = ldsA(LDSU, wn1b + (ks << 9));
        an = mfma16(al, bn, an); an = mfma16(ah, bn, an);
      }
#pragma unroll
      for (int i = 0; i < 4; ++i) an[i] = fast_tanh(an[i] + bn1c + xr2[hf][i] * wn1L);
#pragma unroll
      for (int i = 0; i < 4; ++i) LB[HA_O + wr128[i]] = bf16r(an[i]);
    }
    __syncthreads();
    // g5: n second layer from registers + blend + write st-mean -> HB[16][64]
#pragma unroll
    for (int hf = 0; hf < 2; ++hf){
      unsigned short* LB = LDSU + (hf << 13);
      f32x4 ns = {0.f,0.f,0.f,0.f};
#pragma unroll
      for (int ks = 0; ks < 4; ++ks)
        ns = mfma16(ldsA(LB, HA_O + a128[ks]), n2f[ks], ns);
#pragma unroll
      for (int i = 0; i < 4; ++i){
        float nv = ns[i] + bn2c;
        float uu = u2[hf][i];
        float base = isMean ? yf2[hf][i] : st2[hf][i];
        float nm = (1.0f - uu) * nv + uu * base;
        float fs = mk2[hf][i] * nm + (1.0f - mk2[hf][i]) * base;
        st2[hf][i] = isMean ? fs : fabsf(fs);
      }
      if (isMean){
#pragma unroll
        for (int i = 0; i < 4; ++i) LB[HB_O + wr64[i]] = bf16r(st2[hf][i]);
      }
    }
    __syncthreads();
  }

  // ---------------- store ----------------
#pragma unroll
  for (int hf = 0; hf < 2; ++hf)
#pragma unroll
    for (int i = 0; i < 4; ++i){
      int r = rowBase + 16*hf + rb + i;
      if (isMean) out[r * 64 + c64] = st2[hf][i];
      else        out[524288 + r * 64 + c64] = st2[hf][i];
    }
}

extern "C" void kernel_launch(void* const* d_in, const int* in_sizes, int n_in,
                              void* d_out, int out_size, void* d_ws, size_t ws_size,
                              hipStream_t stream)
{
  (void)in_sizes; (void)n_in; (void)out_size; (void)ws_size;
  unsigned short* pack = (unsigned short*)d_ws;
  prep_pack<<<dim3((PREP_TOT + 255) / 256), dim3(256), 0, stream>>>(
      (const float*)d_in[2],  (const float*)d_in[4],  (const float*)d_in[6],
      (const float*)d_in[8],  (const float*)d_in[12], (const float*)d_in[16],
      (const float*)d_in[10], (const float*)d_in[14], (const float*)d_in[18],
      (const float*)d_in[7],  pack);
  ode_rnn_main<<<dim3(256), dim3(512), 0, stream>>>(
      (const float*)d_in[0],  (const float*)d_in[1],
      (const float*)d_in[3],  (const float*)d_in[5],  (const float*)d_in[7],
      (const float*)d_in[9],  (const float*)d_in[11],
      (const float*)d_in[13], (const float*)d_in[15],
      (const float*)d_in[17], (const float*)d_in[19],
      (const float*)d_in[8],  (const float*)d_in[12], (const float*)d_in[16],
      (const unsigned short*)pack, (float*)d_out);
}

// Round 11
// 1935.259 us; speedup vs baseline: 1.6033x; 1.0602x over previous
//
#include <hip/hip_runtime.h>

typedef __attribute__((ext_vector_type(8))) short bf16x8;
typedef __attribute__((ext_vector_type(4))) float f32x4;

#define T_LEN 256
// pack offsets (short units)
#define OFF_W1   0
#define OFF_W2   8192
#define OFF_W31  24576
#define OFF_W3   40960
#define OFF_WU1  49152
#define OFF_WR1  65536
#define OFF_WN1  81920
#define OFF_WU2  98304
#define OFF_WR2  106496
#define OFF_WN2  114688
#define OFF_B3W1 131072   // f32[128] appended after bf16 packs
#define PREP_TOT 131200

// LDS layout (short units). Two activation halves (8192 shorts each, base hf<<13),
// ONE shared weight stage, plus UX gate-exchange buffers.
// per-half:
#define HA_O   0      // [16][128]
#define HB_O   2048   // [16][128]
#define SGH_O  4096   // [16][128]; first 1024 shorts double as st-mean [16][64]
#define SGL_O  6144   // [16][128]
// shared weight stage = pack[40960..98304):
#define WS_O   16384
#define W3S    16384  // 16 blocks  (8192 shorts)
#define WU1S   24576  // 32 blocks  (16384)
#define WR1S   40960  // 32 blocks  (16384)
#define WN1S   57344  // 32 blocks  (16384) -> ends 73728
#define UX_F   36864  // float units: u gate f32 [2][16][64] (shorts 73728..77823)
#define LDS_SHORTS 77824
#define WS_COPY 7168  // 57344/8 b128 copies

__device__ __forceinline__ float bf16tof(unsigned short u){
  unsigned int v = ((unsigned int)u) << 16;
  return __builtin_bit_cast(float, v);
}
__device__ __forceinline__ unsigned int cvt_pk_bf16(float a, float b){
  unsigned int r;
  asm("v_cvt_pk_bf16_f32 %0, %1, %2" : "=v"(r) : "v"(a), "v"(b));
  return r;   // low16 = bf16(a), high16 = bf16(b)
}
// write 4 bf16 values to 4 sparse LDS indices (2 cvt_pk + 2 shifts)
__device__ __forceinline__ void packw4(unsigned short* b, const int* idx, f32x4 v){
  unsigned int p0 = cvt_pk_bf16(v[0], v[1]);
  unsigned int p1 = cvt_pk_bf16(v[2], v[3]);
  b[idx[0]] = (unsigned short)p0;  b[idx[1]] = (unsigned short)(p0 >> 16);
  b[idx[2]] = (unsigned short)p1;  b[idx[3]] = (unsigned short)(p1 >> 16);
}
// hi/lo split write: v = hi + lo, both bf16
__device__ __forceinline__ void packw4_split(unsigned short* bh, unsigned short* bl,
                                             const int* idx, f32x4 v){
  unsigned int h0 = cvt_pk_bf16(v[0], v[1]);
  unsigned int h1 = cvt_pk_bf16(v[2], v[3]);
  float f0 = __builtin_bit_cast(float, h0 << 16);
  float f1 = __builtin_bit_cast(float, h0 & 0xffff0000u);
  float f2 = __builtin_bit_cast(float, h1 << 16);
  float f3 = __builtin_bit_cast(float, h1 & 0xffff0000u);
  unsigned int l0 = cvt_pk_bf16(v[0] - f0, v[1] - f1);
  unsigned int l1 = cvt_pk_bf16(v[2] - f2, v[3] - f3);
  bh[idx[0]] = (unsigned short)h0;  bh[idx[1]] = (unsigned short)(h0 >> 16);
  bh[idx[2]] = (unsigned short)h1;  bh[idx[3]] = (unsigned short)(h1 >> 16);
  bl[idx[0]] = (unsigned short)l0;  bl[idx[1]] = (unsigned short)(l0 >> 16);
  bl[idx[2]] = (unsigned short)l1;  bl[idx[3]] = (unsigned short)(l1 >> 16);
}
__device__ __forceinline__ float fast_tanh(float x){
  float e = __builtin_amdgcn_exp2f(x * 2.885390081777927f);   // exp(2x)
  return 1.0f - 2.0f * __builtin_amdgcn_rcpf(1.0f + e);
}
__device__ __forceinline__ float fast_sigmoid(float x){
  float e = __builtin_amdgcn_exp2f(x * -1.4426950408889634f); // exp(-x)
  return __builtin_amdgcn_rcpf(1.0f + e);
}
__device__ __forceinline__ f32x4 mfma16(bf16x8 a, bf16x8 b, f32x4 c){
  return __builtin_amdgcn_mfma_f32_16x16x32_bf16(a, b, c, 0, 0, 0);
}
__device__ __forceinline__ bf16x8 load_bfrag(const unsigned short* p, int blk, int lane){
  return *reinterpret_cast<const bf16x8*>(p + ((blk << 6) + lane) * 8);
}
__device__ __forceinline__ bf16x8 ldsA(const unsigned short* LDSU, int idx){
  return *reinterpret_cast<const bf16x8*>(LDSU + idx);
}

// CPU-side bf16 RNE for prep (unchanged semantics from prior rounds)
__device__ __forceinline__ unsigned short bf16r(float f){
  unsigned int x = __builtin_bit_cast(unsigned int, f);
  unsigned int r = (x + 0x7FFFu + ((x >> 16) & 1u)) >> 16;
  return (unsigned short)r;
}

// Pack weights to bf16 MFMA B-fragment order; compute W31=W3@W1, b3W1=b3@W1.
__global__ void prep_pack(const float* __restrict__ W1, const float* __restrict__ W2,
                          const float* __restrict__ W3, const float* __restrict__ Wu1,
                          const float* __restrict__ Wr1, const float* __restrict__ Wn1,
                          const float* __restrict__ Wu2, const float* __restrict__ Wr2,
                          const float* __restrict__ Wn2, const float* __restrict__ b3,
                          unsigned short* __restrict__ pack)
{
  int e = blockIdx.x * blockDim.x + threadIdx.x;
  if (e >= PREP_TOT) return;
  if (e >= OFF_B3W1){
    int j = e - OFF_B3W1;           // 0..127
    float s = 0.0f;
    for (int mm = 0; mm < 64; ++mm) s += b3[mm] * W1[mm * 128 + j];
    ((float*)(pack + OFF_B3W1))[j] = s;
    return;
  }
  const int offs[11] = {0, 8192, 24576, 40960, 49152, 65536, 81920, 98304, 106496, 114688, 131072};
  const int Ks[10] = {64,128,128,128,128,128,128,128,128,128};
  const int Ns[10] = {128,128,128,64,128,128,128,64,64,128};
  int m = 0;
  while (e >= offs[m + 1]) ++m;
  int el = e - offs[m];
  int j = el & 7, lane = (el >> 3) & 63, blk = el >> 9;
  int ksteps = Ks[m] >> 5;
  int ks = blk % ksteps, nt = blk / ksteps;
  int k = ks * 32 + ((lane >> 4) << 3) + j;
  int n = nt * 16 + (lane & 15);
  float v;
  if (m == 2){ // W31[k][n] = sum_mm W3[k][mm] * W1[mm][n]
    float s = 0.0f;
    for (int mm = 0; mm < 64; ++mm) s += W3[k * 64 + mm] * W1[mm * 128 + n];
    v = s;
  } else {
    const float* srcs[10] = {W1, W2, nullptr, W3, Wu1, Wr1, Wn1, Wu2, Wr2, Wn2};
    v = srcs[m][k * Ns[m] + n];
  }
  pack[e] = bf16r(v);
}

__global__ __launch_bounds__(512, 2) void ode_rnn_main(
  const float* __restrict__ bts, const float* __restrict__ mtr,
  const float* __restrict__ b1, const float* __restrict__ b2, const float* __restrict__ b3,
  const float* __restrict__ bu1, const float* __restrict__ bu2,
  const float* __restrict__ br1, const float* __restrict__ br2,
  const float* __restrict__ bn1, const float* __restrict__ bn2,
  const float* __restrict__ Wu1f, const float* __restrict__ Wr1f, const float* __restrict__ Wn1f,
  const unsigned short* __restrict__ pack, float* __restrict__ out)
{
  __shared__ __align__(16) unsigned short LDSU[LDS_SHORTS];
  float* FUR = (float*)LDSU;
  const int tid = threadIdx.x, w = tid >> 6, lane = tid & 63;
  const int arow = lane & 15, g = lane >> 4, rb = g << 2;
  const int c128 = (w << 4) + arow;        // wave's 128-wide column
  const int c64  = ((w & 3) << 4) + arow;  // wave's 64-wide column
  const bool isMean = (w < 4);
  const int rowBase = blockIdx.x * 32;     // 32 rows per WG (two halves)

  // ---- prologue: stage shared weights into LDS ----
#pragma unroll
  for (int i = 0; i < 14; ++i){
    int idx = tid + (i << 9);
    *reinterpret_cast<bf16x8*>(LDSU + WS_O + (idx << 3)) =
        *reinterpret_cast<const bf16x8*>(pack + OFF_W3 + (idx << 3));
  }
  // zero both halves' st-mean buffers (SGH first 1024 shorts each)
  {
    int hf = tid >> 8, idx = tid & 255;
    ((unsigned long long*)(LDSU + (hf << 13) + SGH_O))[idx] = 0ULL;
  }

  // precomputed LDS indices (short units, relative to half base)
  int a128[4], wr128[4], wrmM[4], wr64[4], furi[4], a64v[2];
#pragma unroll
  for (int ks = 0; ks < 4; ++ks) a128[ks] = arow*128 + ((32*ks + 8*g) ^ (arow << 3));
#pragma unroll
  for (int ks = 0; ks < 2; ++ks) a64v[ks] = arow*64 + ((32*ks + 8*g) ^ ((arow & 7) << 3));
#pragma unroll
  for (int i = 0; i < 4; ++i){
    int r = rb + i;
    wr128[i] = r*128 + (c128 ^ (r << 3));
    wrmM[i]  = r*128 + (c64  ^ (r << 3));   // mean-region position of col c64
    wr64[i]  = r*64  + (c64 ^ ((r & 7) << 3));
    furi[i]  = r*64 + c64;
  }
  // staged-weight bases (absolute short units, + ks<<9 per k-step)
  const int wsb  = ((4*w) << 9) + (lane << 3);
  const int w3b  = W3S  + ((4*(w & 3)) << 9) + (lane << 3);
  const int wu1b = WU1S + wsb;
  const int wr1b = WR1S + wsb;
  const int wn1b = WN1S + wsb;

  // persistent per-wave weight fragments (registers, ~72 VGPR)
  bf16x8 w1f[2], w2f[4], w31f[4], g2wf[4], n2f[4];
#pragma unroll
  for (int ks = 0; ks < 2; ++ks) w1f[ks]  = load_bfrag(pack + OFF_W1,  2*w + ks, lane);
#pragma unroll
  for (int ks = 0; ks < 4; ++ks){
    w2f[ks]  = load_bfrag(pack + OFF_W2,  4*w + ks, lane);
    w31f[ks] = load_bfrag(pack + OFF_W31, 4*w + ks, lane);
    g2wf[ks] = load_bfrag(pack + (isMean ? OFF_WU2 : OFF_WR2), 4*(w & 3) + ks, lane);
    n2f[ks]  = load_bfrag(pack + OFF_WN2, 4*w + ks, lane);
  }

  const float* b3w1p = (const float*)(pack + OFF_B3W1);
  const float b1c = b1[c128], b2c = b2[c128], b3c = b3[c64], b3w1c = b3w1p[c128];
  const float bu1c = bu1[c128], br1c = br1[c128], bn1c = bn1[c128], bn2c = bn2[c128];
  const float g2b = isMean ? bu2[c64] : br2[c64];
  const float wu1L = Wu1f[16384 + c128], wr1L = Wr1f[16384 + c128], wn1L = Wn1f[16384 + c128];

  __syncthreads();   // staging + st-zero visible

  f32x4 st2[2], yf2[2], u2[2];
#pragma unroll
  for (int hf = 0; hf < 2; ++hf){
    st2[hf] = (f32x4){0.f,0.f,0.f,0.f};
    yf2[hf] = (f32x4){0.f,0.f,0.f,0.f};
    u2[hf]  = (f32x4){0.f,0.f,0.f,0.f};
  }

#pragma unroll 1
  for (int s = 0; s < T_LEN; ++s){
    const int tj = T_LEN - 1 - s;
    const float t1 = bts[2*tj];
    const float t0 = (s == 0) ? 5.0f : bts[2*tj + 2];
    const float hh = (t1 - t0);            // single RK4 step over the interval

    f32x4 xr2[2], mk2[2];
#pragma unroll
    for (int hf = 0; hf < 2; ++hf)
#pragma unroll
      for (int i = 0; i < 4; ++i){
        int r = rowBase + 16*hf + rb + i;
        xr2[hf][i] = bts[(r * T_LEN + tj) * 2 + 1];
        mk2[hf][i] = mtr[r * T_LEN + tj];
      }

    f32x4 R2[2], Hsum2[2];

    // ---------------- RK4: one substep, 8 phases ----------------
    // p0: h1 stage1 from st-mean (SGH st region, K=64) -> HA
#pragma unroll
    for (int hf = 0; hf < 2; ++hf){
      unsigned short* LB = LDSU + (hf << 13);
      f32x4 acc = (f32x4){b1c, b1c, b1c, b1c};
      acc = mfma16(ldsA(LB, SGH_O + a64v[0]), w1f[0], acc);
      acc = mfma16(ldsA(LB, SGH_O + a64v[1]), w1f[1], acc);
      R2[hf] = acc;
      f32x4 h;
#pragma unroll
      for (int i = 0; i < 4; ++i) h[i] = fast_tanh(acc[i]);
      packw4(LB + HA_O, wr128, h);
    }
    __syncthreads();
    // 3x { h2 stage (HA->SGH) | h1 stage (SGH->HA) }
#pragma unroll
    for (int hs = 0; hs < 3; ++hs){
      const float wgt = (hs == 0) ? 1.0f : 2.0f;
      const float scn = (hs == 2) ? hh : 0.5f * hh;
#pragma unroll
      for (int hf = 0; hf < 2; ++hf){
        unsigned short* LB = LDSU + (hf << 13);
        f32x4 acc = (f32x4){b2c, b2c, b2c, b2c};
#pragma unroll
        for (int ks = 0; ks < 4; ++ks)
          acc = mfma16(ldsA(LB, HA_O + a128[ks]), w2f[ks], acc);
        f32x4 h, hsc;
#pragma unroll
        for (int i = 0; i < 4; ++i) h[i] = fast_tanh(acc[i]);
        if (hs == 0) Hsum2[hf] = h;
        else {
#pragma unroll
          for (int i = 0; i < 4; ++i) Hsum2[hf][i] += wgt * h[i];
        }
#pragma unroll
        for (int i = 0; i < 4; ++i) hsc[i] = h[i] * scn;
        packw4(LB + SGH_O, wr128, hsc);
      }
      __syncthreads();
      const float ac = (hs == 2) ? hh : 0.5f * hh;
#pragma unroll
      for (int hf = 0; hf < 2; ++hf){
        unsigned short* LB = LDSU + (hf << 13);
        f32x4 acc2;
#pragma unroll
        for (int i = 0; i < 4; ++i) acc2[i] = R2[hf][i] + ac * b3w1c;
#pragma unroll
        for (int ks = 0; ks < 4; ++ks)
          acc2 = mfma16(ldsA(LB, SGH_O + a128[ks]), w31f[ks], acc2);
        f32x4 h;
#pragma unroll
        for (int i = 0; i < 4; ++i) h[i] = fast_tanh(acc2[i]);
        packw4(LB + HA_O, wr128, h);
      }
      __syncthreads();
    }
    // p7: h2 stage 4 (HA->), Gsum hi/lo -> HB/SGH
#pragma unroll
    for (int hf = 0; hf < 2; ++hf){
      unsigned short* LB = LDSU + (hf << 13);
      f32x4 acc = (f32x4){b2c, b2c, b2c, b2c};
#pragma unroll
      for (int ks = 0; ks < 4; ++ks)
        acc = mfma16(ldsA(LB, HA_O + a128[ks]), w2f[ks], acc);
      const float sc6 = hh * (1.0f / 6.0f);
      f32x4 gv;
#pragma unroll
      for (int i = 0; i < 4; ++i) gv[i] = (Hsum2[hf][i] + fast_tanh(acc[i])) * sc6;
      packw4_split(LB + HB_O, LB + SGH_O, wr128, gv);
    }
    __syncthreads();
    // Y: mean waves recover mean_ode (W3 stage; reads HB+SGH); all write state hi/lo -> HA/SGL
#pragma unroll
    for (int hf = 0; hf < 2; ++hf){
      unsigned short* LB = LDSU + (hf << 13);
      if (isMean){
        f32x4 acc = {0.f,0.f,0.f,0.f};
#pragma unroll
        for (int ks = 0; ks < 4; ++ks){
          bf16x8 wf = ldsA(LDSU, w3b + (ks << 9));
          acc = mfma16(ldsA(LB, HB_O  + a128[ks]), wf, acc);
          acc = mfma16(ldsA(LB, SGH_O + a128[ks]), wf, acc);
        }
#pragma unroll
        for (int i = 0; i < 4; ++i) yf2[hf][i] = st2[hf][i] + acc[i] + hh * b3c;
        packw4_split(LB + HA_O, LB + SGL_O, wr128, yf2[hf]);
      } else {
        packw4_split(LB + HA_O, LB + SGL_O, wr128, st2[hf]);
      }
    }
    __syncthreads();
    // g1: u & r first layers (read HA/SGL state; write au->HB, ar->SGH)
#pragma unroll
    for (int hf = 0; hf < 2; ++hf){
      unsigned short* LB = LDSU + (hf << 13);
      f32x4 au = {0.f,0.f,0.f,0.f}, ar = {0.f,0.f,0.f,0.f};
#pragma unroll
      for (int ks = 0; ks < 4; ++ks){
        bf16x8 ah = ldsA(LB, HA_O  + a128[ks]);
        bf16x8 al = ldsA(LB, SGL_O + a128[ks]);
        bf16x8 bu = ldsA(LDSU, wu1b + (ks << 9));
        bf16x8 br_ = ldsA(LDSU, wr1b + (ks << 9));
        au = mfma16(al, bu, au);  au = mfma16(ah, bu, au);
        ar = mfma16(al, br_, ar); ar = mfma16(ah, br_, ar);
      }
      f32x4 av, rv;
#pragma unroll
      for (int i = 0; i < 4; ++i){
        av[i] = fast_tanh(au[i] + bu1c + xr2[hf][i] * wu1L);
        rv[i] = fast_tanh(ar[i] + br1c + xr2[hf][i] * wr1L);
      }
      packw4(LB + HB_O,  wr128, av);
      packw4(LB + SGH_O, wr128, rv);
    }
    __syncthreads();
    // g2' (merged g2+g3): second layers; mean -> u (publish to UX);
    // std -> rr AND both gated states yc written to HA/SGL (reads own yf first)
#pragma unroll
    for (int hf = 0; hf < 2; ++hf){
      unsigned short* LB = LDSU + (hf << 13);
      f32x4 acc = {0.f,0.f,0.f,0.f};
      const int srcO = isMean ? HB_O : SGH_O;
#pragma unroll
      for (int ks = 0; ks < 4; ++ks)
        acc = mfma16(ldsA(LB, srcO + a128[ks]), g2wf[ks], acc);
      if (isMean){
#pragma unroll
        for (int i = 0; i < 4; ++i){
          u2[hf][i] = fast_sigmoid(acc[i] + g2b);
          FUR[UX_F + (hf << 10) + furi[i]] = u2[hf][i];
        }
      } else {
        f32x4 ycm, ycs;
#pragma unroll
        for (int i = 0; i < 4; ++i){
          float rr = fast_sigmoid(acc[i] + g2b);
          float yfv = bf16tof(LB[HA_O + wrmM[i]]) + bf16tof(LB[SGL_O + wrmM[i]]);
          ycm[i] = yfv * rr;
          ycs[i] = st2[hf][i] * rr;
        }
        packw4_split(LB + HA_O, LB + SGL_O, wrmM,  ycm);
        packw4_split(LB + HA_O, LB + SGL_O, wr128, ycs);
      }
    }
    __syncthreads();
    // g4: n first layer (read HA/SGL yc; write an -> HB)
#pragma unroll
    for (int hf = 0; hf < 2; ++hf){
      unsigned short* LB = LDSU + (hf << 13);
      f32x4 an = {0.f,0.f,0.f,0.f};
#pragma unroll
      for (int ks = 0; ks < 4; ++ks){
        bf16x8 ah = ldsA(LB, HA_O  + a128[ks]);
        bf16x8 al = ldsA(LB, SGL_O + a128[ks]);
        bf16x8 bn = ldsA(LDSU, wn1b + (ks << 9));
        an = mfma16(al, bn, an); an = mfma16(ah, bn, an);
      }
      f32x4 av;
#pragma unroll
      for (int i = 0; i < 4; ++i) av[i] = fast_tanh(an[i] + bn1c + xr2[hf][i] * wn1L);
      packw4(LB + HB_O, wr128, av);
    }
    __syncthreads();
    // g5: n second layer (read HB) + blend + write st-mean -> SGH st region
#pragma unroll
    for (int hf = 0; hf < 2; ++hf){
      unsigned short* LB = LDSU + (hf << 13);
      f32x4 ns = {0.f,0.f,0.f,0.f};
#pragma unroll
      for (int ks = 0; ks < 4; ++ks)
        ns = mfma16(ldsA(LB, HA_O + a128[ks] - HA_O + HB_O), n2f[ks], ns);
      f32x4 uu;
      if (isMean) uu = u2[hf];
      else {
#pragma unroll
        for (int i = 0; i < 4; ++i) uu[i] = FUR[UX_F + (hf << 10) + furi[i]];
      }
#pragma unroll
      for (int i = 0; i < 4; ++i){
        float nv = ns[i] + bn2c;
        float base = isMean ? yf2[hf][i] : st2[hf][i];
        float nm = (1.0f - uu[i]) * nv + uu[i] * base;
        float fs = mk2[hf][i] * nm + (1.0f - mk2[hf][i]) * base;
        st2[hf][i] = isMean ? fs : fabsf(fs);
      }
      if (isMean) packw4(LB + SGH_O, wr64, st2[hf]);
    }
    __syncthreads();
  }

  // ---------------- store ----------------
#pragma unroll
  for (int hf = 0; hf < 2; ++hf)
#pragma unroll
    for (int i = 0; i < 4; ++i){
      int r = rowBase + 16*hf + rb + i;
      if (isMean) out[r * 64 + c64] = st2[hf][i];
      else        out[524288 + r * 64 + c64] = st2[hf][i];
    }
}

extern "C" void kernel_launch(void* const* d_in, const int* in_sizes, int n_in,
                              void* d_out, int out_size, void* d_ws, size_t ws_size,
                              hipStream_t stream)
{
  (void)in_sizes; (void)n_in; (void)out_size; (void)ws_size;
  unsigned short* pack = (unsigned short*)d_ws;
  prep_pack<<<dim3((PREP_TOT + 255) / 256), dim3(256), 0, stream>>>(
      (const float*)d_in[2],  (const float*)d_in[4],  (const float*)d_in[6],
      (const float*)d_in[8],  (const float*)d_in[12], (const float*)d_in[16],
      (const float*)d_in[10], (const float*)d_in[14], (const float*)d_in[18],
      (const float*)d_in[7],  pack);
  ode_rnn_main<<<dim3(256), dim3(512), 0, stream>>>(
      (const float*)d_in[0],  (const float*)d_in[1],
      (const float*)d_in[3],  (const float*)d_in[5],  (const float*)d_in[7],
      (const float*)d_in[9],  (const float*)d_in[11],
      (const float*)d_in[13], (const float*)d_in[15],
      (const float*)d_in[17], (const float*)d_in[19],
      (const float*)d_in[8],  (const float*)d_in[12], (const float*)d_in[16],
      (const unsigned short*)pack, (float*)d_out);
}

// Round 12
// 1451.930 us; speedup vs baseline: 2.1370x; 1.3329x over previous
//
#include <hip/hip_runtime.h>

typedef __attribute__((ext_vector_type(8))) short bf16x8;
typedef __attribute__((ext_vector_type(4))) float f32x4;

#define T_LEN 256
#define LAM    2.885390081777927f    // 2*log2(e): tanh pre-scale
#define NL2E  -1.4426950408889634f   // -log2(e): sigmoid pre-scale
// pack offsets (short units)
#define OFF_W1   0
#define OFF_W2   8192
#define OFF_W31  24576
#define OFF_W3   40960
#define OFF_WU1  49152
#define OFF_WR1  65536
#define OFF_WN1  81920
#define OFF_WU2  98304
#define OFF_WR2  106496
#define OFF_WN2  114688
#define OFF_B3W1 131072   // f32[128] appended after bf16 packs
#define PREP_TOT 131200

// LDS layout (short units). Two activation halves (8192 shorts each, base hf<<13),
// ONE shared weight stage, plus UX gate-exchange buffer.
// per-half:
#define HA_O   0      // [16][128]
#define HB_O   2048   // [16][128]
#define SGH_O  4096   // [16][128]; first 1024 shorts double as st-mean [16][64]
#define SGL_O  6144   // [16][128]
// shared weight stage = pack[40960..98304):
#define WS_O   16384
#define W3S    16384  // 16 blocks  (8192 shorts)
#define WU1S   24576  // 32 blocks  (16384)
#define WR1S   40960  // 32 blocks  (16384)
#define WN1S   57344  // 32 blocks  (16384) -> ends 73728
#define UX_F   36864  // float units: u gate f32 [2][16][64] (shorts 73728..77823)
#define LDS_SHORTS 77824

__device__ __forceinline__ float bf16tof(unsigned short u){
  unsigned int v = ((unsigned int)u) << 16;
  return __builtin_bit_cast(float, v);
}
__device__ __forceinline__ unsigned int cvt_pk_bf16(float a, float b){
  unsigned int r;
  asm("v_cvt_pk_bf16_f32 %0, %1, %2" : "=v"(r) : "v"(a), "v"(b));
  return r;   // low16 = bf16(a), high16 = bf16(b)
}
__device__ __forceinline__ void packw4(unsigned short* b, const int* idx, f32x4 v){
  unsigned int p0 = cvt_pk_bf16(v[0], v[1]);
  unsigned int p1 = cvt_pk_bf16(v[2], v[3]);
  b[idx[0]] = (unsigned short)p0;  b[idx[1]] = (unsigned short)(p0 >> 16);
  b[idx[2]] = (unsigned short)p1;  b[idx[3]] = (unsigned short)(p1 >> 16);
}
__device__ __forceinline__ void packw4_split(unsigned short* bh, unsigned short* bl,
                                             const int* idx, f32x4 v){
  unsigned int h0 = cvt_pk_bf16(v[0], v[1]);
  unsigned int h1 = cvt_pk_bf16(v[2], v[3]);
  float f0 = __builtin_bit_cast(float, h0 << 16);
  float f1 = __builtin_bit_cast(float, h0 & 0xffff0000u);
  float f2 = __builtin_bit_cast(float, h1 << 16);
  float f3 = __builtin_bit_cast(float, h1 & 0xffff0000u);
  unsigned int l0 = cvt_pk_bf16(v[0] - f0, v[1] - f1);
  unsigned int l1 = cvt_pk_bf16(v[2] - f2, v[3] - f3);
  bh[idx[0]] = (unsigned short)h0;  bh[idx[1]] = (unsigned short)(h0 >> 16);
  bh[idx[2]] = (unsigned short)h1;  bh[idx[3]] = (unsigned short)(h1 >> 16);
  bl[idx[0]] = (unsigned short)l0;  bl[idx[1]] = (unsigned short)(l0 >> 16);
  bl[idx[2]] = (unsigned short)l1;  bl[idx[3]] = (unsigned short)(l1 >> 16);
}
// inputs pre-scaled by LAM / NL2E respectively
__device__ __forceinline__ float tanh_p(float x){
  return 1.0f - 2.0f * __builtin_amdgcn_rcpf(1.0f + __builtin_amdgcn_exp2f(x));
}
__device__ __forceinline__ float sig_p(float x){
  return __builtin_amdgcn_rcpf(1.0f + __builtin_amdgcn_exp2f(x));
}
__device__ __forceinline__ f32x4 mfma16(bf16x8 a, bf16x8 b, f32x4 c){
  return __builtin_amdgcn_mfma_f32_16x16x32_bf16(a, b, c, 0, 0, 0);
}
__device__ __forceinline__ bf16x8 load_bfrag(const unsigned short* p, int blk, int lane){
  return *reinterpret_cast<const bf16x8*>(p + ((blk << 6) + lane) * 8);
}
__device__ __forceinline__ bf16x8 ldsA(const unsigned short* LDSU, int idx){
  return *reinterpret_cast<const bf16x8*>(LDSU + idx);
}
__device__ __forceinline__ unsigned short bf16r(float f){
  unsigned int x = __builtin_bit_cast(unsigned int, f);
  unsigned int r = (x + 0x7FFFu + ((x >> 16) & 1u)) >> 16;
  return (unsigned short)r;
}

// Pack weights to bf16 MFMA B-fragment order with transcendental pre-scales;
// compute W31=W3@W1 (x LAM), b3W1=b3@W1 (x LAM).
__global__ void prep_pack(const float* __restrict__ W1, const float* __restrict__ W2,
                          const float* __restrict__ W3, const float* __restrict__ Wu1,
                          const float* __restrict__ Wr1, const float* __restrict__ Wn1,
                          const float* __restrict__ Wu2, const float* __restrict__ Wr2,
                          const float* __restrict__ Wn2, const float* __restrict__ b3,
                          unsigned short* __restrict__ pack)
{
  int e = blockIdx.x * blockDim.x + threadIdx.x;
  if (e >= PREP_TOT) return;
  if (e >= OFF_B3W1){
    int j = e - OFF_B3W1;           // 0..127
    float s = 0.0f;
    for (int mm = 0; mm < 64; ++mm) s += b3[mm] * W1[mm * 128 + j];
    ((float*)(pack + OFF_B3W1))[j] = s * LAM;
    return;
  }
  const int offs[11] = {0, 8192, 24576, 40960, 49152, 65536, 81920, 98304, 106496, 114688, 131072};
  const int Ks[10] = {64,128,128,128,128,128,128,128,128,128};
  const int Ns[10] = {128,128,128,64,128,128,128,64,64,128};
  const float scl[10] = {LAM, LAM, LAM, 1.0f, LAM, LAM, LAM, NL2E, NL2E, 1.0f};
  int m = 0;
  while (e >= offs[m + 1]) ++m;
  int el = e - offs[m];
  int j = el & 7, lane = (el >> 3) & 63, blk = el >> 9;
  int ksteps = Ks[m] >> 5;
  int ks = blk % ksteps, nt = blk / ksteps;
  int k = ks * 32 + ((lane >> 4) << 3) + j;
  int n = nt * 16 + (lane & 15);
  float v;
  if (m == 2){ // W31[k][n] = sum_mm W3[k][mm] * W1[mm][n]
    float s = 0.0f;
    for (int mm = 0; mm < 64; ++mm) s += W3[k * 64 + mm] * W1[mm * 128 + n];
    v = s;
  } else {
    const float* srcs[10] = {W1, W2, nullptr, W3, Wu1, Wr1, Wn1, Wu2, Wr2, Wn2};
    v = srcs[m][k * Ns[m] + n];
  }
  pack[e] = bf16r(v * scl[m]);
}

__global__ __launch_bounds__(512, 2) void ode_rnn_main(
  const float* __restrict__ bts, const float* __restrict__ mtr,
  const float* __restrict__ b1, const float* __restrict__ b2, const float* __restrict__ b3,
  const float* __restrict__ bu1, const float* __restrict__ bu2,
  const float* __restrict__ br1, const float* __restrict__ br2,
  const float* __restrict__ bn1, const float* __restrict__ bn2,
  const float* __restrict__ Wu1f, const float* __restrict__ Wr1f, const float* __restrict__ Wn1f,
  const unsigned short* __restrict__ pack, float* __restrict__ out)
{
  __shared__ __align__(16) unsigned short LDSU[LDS_SHORTS];
  float* FUR = (float*)LDSU;
  const int tid = threadIdx.x, w = tid >> 6, lane = tid & 63;
  const int arow = lane & 15, g = lane >> 4, rb = g << 2;
  const int c128 = (w << 4) + arow;
  const int c64  = ((w & 3) << 4) + arow;
  const bool isMean = (w < 4);
  const int rowBase = blockIdx.x * 32;     // 32 rows per WG (two halves)

  // ---- prologue: stage shared weights into LDS ----
#pragma unroll
  for (int i = 0; i < 14; ++i){
    int idx = tid + (i << 9);
    *reinterpret_cast<bf16x8*>(LDSU + WS_O + (idx << 3)) =
        *reinterpret_cast<const bf16x8*>(pack + OFF_W3 + (idx << 3));
  }
  // zero both halves' st-mean buffers (SGH first 1024 shorts each)
  {
    int hf = tid >> 8, idx = tid & 255;
    ((unsigned long long*)(LDSU + (hf << 13) + SGH_O))[idx] = 0ULL;
  }

  // precomputed LDS indices (short units, relative to half base)
  int a128[4], wr128[4], wrmM[4], wr64[4], furi[4], a64v[2];
#pragma unroll
  for (int ks = 0; ks < 4; ++ks) a128[ks] = arow*128 + ((32*ks + 8*g) ^ (arow << 3));
#pragma unroll
  for (int ks = 0; ks < 2; ++ks) a64v[ks] = arow*64 + ((32*ks + 8*g) ^ ((arow & 7) << 3));
#pragma unroll
  for (int i = 0; i < 4; ++i){
    int r = rb + i;
    wr128[i] = r*128 + (c128 ^ (r << 3));
    wrmM[i]  = r*128 + (c64  ^ (r << 3));
    wr64[i]  = r*64  + (c64 ^ ((r & 7) << 3));
    furi[i]  = r*64 + c64;
  }
  // staged-weight bases (absolute short units, + ks<<9 per k-step)
  const int wsb  = ((4*w) << 9) + (lane << 3);
  const int w3b  = W3S  + ((4*(w & 3)) << 9) + (lane << 3);
  const int wu1b = WU1S + wsb;
  const int wr1b = WR1S + wsb;
  const int wn1b = WN1S + wsb;

  // persistent per-wave weight fragments (registers)
  bf16x8 w1f[2], w2f[4], w31f[4], g2wf[4], n2f[4];
#pragma unroll
  for (int ks = 0; ks < 2; ++ks) w1f[ks]  = load_bfrag(pack + OFF_W1,  2*w + ks, lane);
#pragma unroll
  for (int ks = 0; ks < 4; ++ks){
    w2f[ks]  = load_bfrag(pack + OFF_W2,  4*w + ks, lane);
    w31f[ks] = load_bfrag(pack + OFF_W31, 4*w + ks, lane);
    g2wf[ks] = load_bfrag(pack + (isMean ? OFF_WU2 : OFF_WR2), 4*(w & 3) + ks, lane);
    n2f[ks]  = load_bfrag(pack + OFF_WN2, 4*w + ks, lane);
  }

  const float* b3w1p = (const float*)(pack + OFF_B3W1);
  const float b1c = b1[c128] * LAM, b2c = b2[c128] * LAM;
  const float b3c = b3[c64], b3w1c = b3w1p[c128];
  const float bu1c = bu1[c128] * LAM, br1c = br1[c128] * LAM;
  const float bn1c = bn1[c128] * LAM, bn2c = bn2[c128];
  const float g2b = (isMean ? bu2[c64] : br2[c64]) * NL2E;
  const float wu1L = Wu1f[16384 + c128] * LAM, wr1L = Wr1f[16384 + c128] * LAM;
  const float wn1L = Wn1f[16384 + c128] * LAM;

  __syncthreads();   // staging + st-zero visible

  f32x4 st2[2], yf2[2], u2[2];
#pragma unroll
  for (int hf = 0; hf < 2; ++hf){
    st2[hf] = (f32x4){0.f,0.f,0.f,0.f};
    yf2[hf] = (f32x4){0.f,0.f,0.f,0.f};
    u2[hf]  = (f32x4){0.f,0.f,0.f,0.f};
  }

#pragma unroll 1
  for (int s = 0; s < T_LEN; ++s){
    const int tj = T_LEN - 1 - s;
    const float t1 = bts[2*tj];
    const float t0 = (s == 0) ? 5.0f : bts[2*tj + 2];
    const float hh = (t1 - t0);            // single RK2-midpoint step per interval

    f32x4 xr2[2], mk2[2];
#pragma unroll
    for (int hf = 0; hf < 2; ++hf)
#pragma unroll
      for (int i = 0; i < 4; ++i){
        int r = rowBase + 16*hf + rb + i;
        xr2[hf][i] = bts[(r * T_LEN + tj) * 2 + 1];
        mk2[hf][i] = mtr[r * T_LEN + tj];
      }

    f32x4 R2[2];

    // ---------------- RK2 midpoint: 4 phases ----------------
    // p0: h1_1 = tanh(st@W1+b1) (K=64 from SGH st region) -> HA; R = pre-activation
#pragma unroll
    for (int hf = 0; hf < 2; ++hf){
      unsigned short* LB = LDSU + (hf << 13);
      f32x4 acc = (f32x4){b1c, b1c, b1c, b1c};
      acc = mfma16(ldsA(LB, SGH_O + a64v[0]), w1f[0], acc);
      acc = mfma16(ldsA(LB, SGH_O + a64v[1]), w1f[1], acc);
      R2[hf] = acc;
      f32x4 h;
#pragma unroll
      for (int i = 0; i < 4; ++i) h[i] = tanh_p(acc[i]);
      packw4(LB + HA_O, wr128, h);
    }
    __syncthreads();
    // p1: h2_1 = tanh(h1_1@W2+b2); write (hh/2)*h2_1 -> SGH
#pragma unroll
    for (int hf = 0; hf < 2; ++hf){
      unsigned short* LB = LDSU + (hf << 13);
      f32x4 acc = (f32x4){b2c, b2c, b2c, b2c};
#pragma unroll
      for (int ks = 0; ks < 4; ++ks)
        acc = mfma16(ldsA(LB, HA_O + a128[ks]), w2f[ks], acc);
      f32x4 hsc;
#pragma unroll
      for (int i = 0; i < 4; ++i) hsc[i] = tanh_p(acc[i]) * (0.5f * hh);
      packw4(LB + SGH_O, wr128, hsc);
    }
    __syncthreads();
    // p2: h1_2 = tanh(R + (hh/2)*(k1@W1-space)) via W31 -> HA
#pragma unroll
    for (int hf = 0; hf < 2; ++hf){
      unsigned short* LB = LDSU + (hf << 13);
      f32x4 acc2;
#pragma unroll
      for (int i = 0; i < 4; ++i) acc2[i] = R2[hf][i] + (0.5f * hh) * b3w1c;
#pragma unroll
      for (int ks = 0; ks < 4; ++ks)
        acc2 = mfma16(ldsA(LB, SGH_O + a128[ks]), w31f[ks], acc2);
      f32x4 h;
#pragma unroll
      for (int i = 0; i < 4; ++i) h[i] = tanh_p(acc2[i]);
      packw4(LB + HA_O, wr128, h);
    }
    __syncthreads();
    // p3: h2_2 = tanh(h1_2@W2+b2); gv = hh*h2_2 hi/lo -> HB/SGH
#pragma unroll
    for (int hf = 0; hf < 2; ++hf){
      unsigned short* LB = LDSU + (hf << 13);
      f32x4 acc = (f32x4){b2c, b2c, b2c, b2c};
#pragma unroll
      for (int ks = 0; ks < 4; ++ks)
        acc = mfma16(ldsA(LB, HA_O + a128[ks]), w2f[ks], acc);
      f32x4 gv;
#pragma unroll
      for (int i = 0; i < 4; ++i) gv[i] = tanh_p(acc[i]) * hh;
      packw4_split(LB + HB_O, LB + SGH_O, wr128, gv);
    }
    __syncthreads();
    // Y: mean waves recover mean_ode; all write state hi/lo -> HA/SGL
#pragma unroll
    for (int hf = 0; hf < 2; ++hf){
      unsigned short* LB = LDSU + (hf << 13);
      if (isMean){
        f32x4 acc = {0.f,0.f,0.f,0.f};
#pragma unroll
        for (int ks = 0; ks < 4; ++ks){
          bf16x8 wf = ldsA(LDSU, w3b + (ks << 9));
          acc = mfma16(ldsA(LB, HB_O  + a128[ks]), wf, acc);
          acc = mfma16(ldsA(LB, SGH_O + a128[ks]), wf, acc);
        }
#pragma unroll
        for (int i = 0; i < 4; ++i) yf2[hf][i] = st2[hf][i] + acc[i] + hh * b3c;
        packw4_split(LB + HA_O, LB + SGL_O, wr128, yf2[hf]);
      } else {
        packw4_split(LB + HA_O, LB + SGL_O, wr128, st2[hf]);
      }
    }
    __syncthreads();
    // g1: u & r first layers (read HA/SGL state; write au->HB, ar->SGH)
#pragma unroll
    for (int hf = 0; hf < 2; ++hf){
      unsigned short* LB = LDSU + (hf << 13);
      f32x4 au = {0.f,0.f,0.f,0.f}, ar = {0.f,0.f,0.f,0.f};
#pragma unroll
      for (int ks = 0; ks < 4; ++ks){
        bf16x8 ah = ldsA(LB, HA_O  + a128[ks]);
        bf16x8 al = ldsA(LB, SGL_O + a128[ks]);
        bf16x8 bu = ldsA(LDSU, wu1b + (ks << 9));
        bf16x8 br_ = ldsA(LDSU, wr1b + (ks << 9));
        au = mfma16(al, bu, au);  au = mfma16(ah, bu, au);
        ar = mfma16(al, br_, ar); ar = mfma16(ah, br_, ar);
      }
      f32x4 av, rv;
#pragma unroll
      for (int i = 0; i < 4; ++i){
        av[i] = tanh_p(au[i] + bu1c + xr2[hf][i] * wu1L);
        rv[i] = tanh_p(ar[i] + br1c + xr2[hf][i] * wr1L);
      }
      packw4(LB + HB_O,  wr128, av);
      packw4(LB + SGH_O, wr128, rv);
    }
    __syncthreads();
    // g2' (merged g2+g3): second layers; mean -> u (publish UX);
    // std -> rr AND both gated states yc written to HA/SGL
#pragma unroll
    for (int hf = 0; hf < 2; ++hf){
      unsigned short* LB = LDSU + (hf << 13);
      f32x4 acc = {0.f,0.f,0.f,0.f};
      const int srcO = isMean ? HB_O : SGH_O;
#pragma unroll
      for (int ks = 0; ks < 4; ++ks)
        acc = mfma16(ldsA(LB, srcO + a128[ks]), g2wf[ks], acc);
      if (isMean){
#pragma unroll
        for (int i = 0; i < 4; ++i){
          u2[hf][i] = sig_p(acc[i] + g2b);
          FUR[UX_F + (hf << 10) + furi[i]] = u2[hf][i];
        }
      } else {
        f32x4 ycm, ycs;
#pragma unroll
        for (int i = 0; i < 4; ++i){
          float rr = sig_p(acc[i] + g2b);
          float yfv = bf16tof(LB[HA_O + wrmM[i]]) + bf16tof(LB[SGL_O + wrmM[i]]);
          ycm[i] = yfv * rr;
          ycs[i] = st2[hf][i] * rr;
        }
        packw4_split(LB + HA_O, LB + SGL_O, wrmM,  ycm);
        packw4_split(LB + HA_O, LB + SGL_O, wr128, ycs);
      }
    }
    __syncthreads();
    // g4: n first layer (read HA/SGL yc; write an -> HB)
#pragma unroll
    for (int hf = 0; hf < 2; ++hf){
      unsigned short* LB = LDSU + (hf << 13);
      f32x4 an = {0.f,0.f,0.f,0.f};
#pragma unroll
      for (int ks = 0; ks < 4; ++ks){
        bf16x8 ah = ldsA(LB, HA_O  + a128[ks]);
        bf16x8 al = ldsA(LB, SGL_O + a128[ks]);
        bf16x8 bn = ldsA(LDSU, wn1b + (ks << 9));
        an = mfma16(al, bn, an); an = mfma16(ah, bn, an);
      }
      f32x4 av;
#pragma unroll
      for (int i = 0; i < 4; ++i) av[i] = tanh_p(an[i] + bn1c + xr2[hf][i] * wn1L);
      packw4(LB + HB_O, wr128, av);
    }
    __syncthreads();
    // g5: n second layer (read HB) + blend + write st-mean -> SGH st region
#pragma unroll
    for (int hf = 0; hf < 2; ++hf){
      unsigned short* LB = LDSU + (hf << 13);
      f32x4 ns = {0.f,0.f,0.f,0.f};
#pragma unroll
      for (int ks = 0; ks < 4; ++ks)
        ns = mfma16(ldsA(LB, HB_O + a128[ks]), n2f[ks], ns);
      f32x4 uu;
      if (isMean) uu = u2[hf];
      else {
#pragma unroll
        for (int i = 0; i < 4; ++i) uu[i] = FUR[UX_F + (hf << 10) + furi[i]];
      }
#pragma unroll
      for (int i = 0; i < 4; ++i){
        float nv = ns[i] + bn2c;
        float base = isMean ? yf2[hf][i] : st2[hf][i];
        float nm = (1.0f - uu[i]) * nv + uu[i] * base;
        float fs = mk2[hf][i] * nm + (1.0f - mk2[hf][i]) * base;
        st2[hf][i] = isMean ? fs : fabsf(fs);
      }
      if (isMean) packw4(LB + SGH_O, wr64, st2[hf]);
    }
    __syncthreads();
  }

  // ---------------- store ----------------
#pragma unroll
  for (int hf = 0; hf < 2; ++hf)
#pragma unroll
    for (int i = 0; i < 4; ++i){
      int r = rowBase + 16*hf + rb + i;
      if (isMean) out[r * 64 + c64] = st2[hf][i];
      else        out[524288 + r * 64 + c64] = st2[hf][i];
    }
}

extern "C" void kernel_launch(void* const* d_in, const int* in_sizes, int n_in,
                              void* d_out, int out_size, void* d_ws, size_t ws_size,
                              hipStream_t stream)
{
  (void)in_sizes; (void)n_in; (void)out_size; (void)ws_size;
  unsigned short* pack = (unsigned short*)d_ws;
  prep_pack<<<dim3((PREP_TOT + 255) / 256), dim3(256), 0, stream>>>(
      (const float*)d_in[2],  (const float*)d_in[4],  (const float*)d_in[6],
      (const float*)d_in[8],  (const float*)d_in[12], (const float*)d_in[16],
      (const float*)d_in[10], (const float*)d_in[14], (const float*)d_in[18],
      (const float*)d_in[7],  pack);
  ode_rnn_main<<<dim3(256), dim3(512), 0, stream>>>(
      (const float*)d_in[0],  (const float*)d_in[1],
      (const float*)d_in[3],  (const float*)d_in[5],  (const float*)d_in[7],
      (const float*)d_in[9],  (const float*)d_in[11],
      (const float*)d_in[13], (const float*)d_in[15],
      (const float*)d_in[17], (const float*)d_in[19],
      (const float*)d_in[8],  (const float*)d_in[12], (const float*)d_in[16],
      (const unsigned short*)pack, (float*)d_out);
}

// Round 13
// 1234.412 us; speedup vs baseline: 2.5135x; 1.1762x over previous
//
#include <hip/hip_runtime.h>

typedef __attribute__((ext_vector_type(8))) short bf16x8;
typedef __attribute__((ext_vector_type(4))) float f32x4;

#define T_LEN 256
#define LAM    2.885390081777927f    // 2*log2(e): tanh pre-scale
#define NL2E  -1.4426950408889634f   // -log2(e): sigmoid pre-scale
// pack offsets (short units)
#define OFF_W1   0
#define OFF_W2   8192
#define OFF_W31  24576
#define OFF_W3   40960
#define OFF_WU1  49152
#define OFF_WR1  65536
#define OFF_WN1  81920
#define OFF_WU2  98304
#define OFF_WR2  106496
#define OFF_WN2  114688
#define OFF_B3W1 131072   // f32[128] appended after bf16 packs
#define PREP_TOT 131200

// LDS layout (short units). Two activation halves (8192 shorts each, base hf<<13),
// ONE shared weight stage, plus UX gate-exchange buffer.
// per-half:
#define HA_O   0      // [16][128]
#define HB_O   2048   // [16][128]
#define SGH_O  4096   // [16][128]; first 1024 shorts double as st-mean [16][64]
#define SGL_O  6144   // [16][128]
// shared weight stage = pack[40960..98304):
#define WS_O   16384
#define W3S    16384  // 16 blocks  (8192 shorts)
#define WU1S   24576  // 32 blocks  (16384)
#define WR1S   40960  // 32 blocks  (16384)
#define WN1S   57344  // 32 blocks  (16384) -> ends 73728
#define UX_F   36864  // float units: u gate f32 [2][16][64] (shorts 73728..77823)
#define LDS_SHORTS 77824

__device__ __forceinline__ float bf16tof(unsigned short u){
  unsigned int v = ((unsigned int)u) << 16;
  return __builtin_bit_cast(float, v);
}
__device__ __forceinline__ unsigned int cvt_pk_bf16(float a, float b){
  unsigned int r;
  asm("v_cvt_pk_bf16_f32 %0, %1, %2" : "=v"(r) : "v"(a), "v"(b));
  return r;   // low16 = bf16(a), high16 = bf16(b)
}
__device__ __forceinline__ void packw4(unsigned short* b, const int* idx, f32x4 v){
  unsigned int p0 = cvt_pk_bf16(v[0], v[1]);
  unsigned int p1 = cvt_pk_bf16(v[2], v[3]);
  b[idx[0]] = (unsigned short)p0;  b[idx[1]] = (unsigned short)(p0 >> 16);
  b[idx[2]] = (unsigned short)p1;  b[idx[3]] = (unsigned short)(p1 >> 16);
}
__device__ __forceinline__ void packw4_split(unsigned short* bh, unsigned short* bl,
                                             const int* idx, f32x4 v){
  unsigned int h0 = cvt_pk_bf16(v[0], v[1]);
  unsigned int h1 = cvt_pk_bf16(v[2], v[3]);
  float f0 = __builtin_bit_cast(float, h0 << 16);
  float f1 = __builtin_bit_cast(float, h0 & 0xffff0000u);
  float f2 = __builtin_bit_cast(float, h1 << 16);
  float f3 = __builtin_bit_cast(float, h1 & 0xffff0000u);
  unsigned int l0 = cvt_pk_bf16(v[0] - f0, v[1] - f1);
  unsigned int l1 = cvt_pk_bf16(v[2] - f2, v[3] - f3);
  bh[idx[0]] = (unsigned short)h0;  bh[idx[1]] = (unsigned short)(h0 >> 16);
  bh[idx[2]] = (unsigned short)h1;  bh[idx[3]] = (unsigned short)(h1 >> 16);
  bl[idx[0]] = (unsigned short)l0;  bl[idx[1]] = (unsigned short)(l0 >> 16);
  bl[idx[2]] = (unsigned short)l1;  bl[idx[3]] = (unsigned short)(l1 >> 16);
}
// inputs pre-scaled by LAM / NL2E respectively
__device__ __forceinline__ float tanh_p(float x){
  return 1.0f - 2.0f * __builtin_amdgcn_rcpf(1.0f + __builtin_amdgcn_exp2f(x));
}
__device__ __forceinline__ float sig_p(float x){
  return __builtin_amdgcn_rcpf(1.0f + __builtin_amdgcn_exp2f(x));
}
__device__ __forceinline__ f32x4 mfma16(bf16x8 a, bf16x8 b, f32x4 c){
  return __builtin_amdgcn_mfma_f32_16x16x32_bf16(a, b, c, 0, 0, 0);
}
__device__ __forceinline__ bf16x8 load_bfrag(const unsigned short* p, int blk, int lane){
  return *reinterpret_cast<const bf16x8*>(p + ((blk << 6) + lane) * 8);
}
__device__ __forceinline__ bf16x8 ldsA(const unsigned short* LDSU, int idx){
  return *reinterpret_cast<const bf16x8*>(LDSU + idx);
}
__device__ __forceinline__ unsigned short bf16r(float f){
  unsigned int x = __builtin_bit_cast(unsigned int, f);
  unsigned int r = (x + 0x7FFFu + ((x >> 16) & 1u)) >> 16;
  return (unsigned short)r;
}

// Pack weights to bf16 MFMA B-fragment order with transcendental pre-scales.
__global__ void prep_pack(const float* __restrict__ W1, const float* __restrict__ W2,
                          const float* __restrict__ W3, const float* __restrict__ Wu1,
                          const float* __restrict__ Wr1, const float* __restrict__ Wn1,
                          const float* __restrict__ Wu2, const float* __restrict__ Wr2,
                          const float* __restrict__ Wn2, const float* __restrict__ b3,
                          unsigned short* __restrict__ pack)
{
  int e = blockIdx.x * blockDim.x + threadIdx.x;
  if (e >= PREP_TOT) return;
  if (e >= OFF_B3W1){
    int j = e - OFF_B3W1;           // 0..127
    float s = 0.0f;
    for (int mm = 0; mm < 64; ++mm) s += b3[mm] * W1[mm * 128 + j];
    ((float*)(pack + OFF_B3W1))[j] = s * LAM;
    return;
  }
  const int offs[11] = {0, 8192, 24576, 40960, 49152, 65536, 81920, 98304, 106496, 114688, 131072};
  const int Ks[10] = {64,128,128,128,128,128,128,128,128,128};
  const int Ns[10] = {128,128,128,64,128,128,128,64,64,128};
  const float scl[10] = {LAM, LAM, LAM, 1.0f, LAM, LAM, LAM, NL2E, NL2E, 1.0f};
  int m = 0;
  while (e >= offs[m + 1]) ++m;
  int el = e - offs[m];
  int j = el & 7, lane = (el >> 3) & 63, blk = el >> 9;
  int ksteps = Ks[m] >> 5;
  int ks = blk % ksteps, nt = blk / ksteps;
  int k = ks * 32 + ((lane >> 4) << 3) + j;
  int n = nt * 16 + (lane & 15);
  float v;
  if (m == 2){ // W31 (unused by Euler main; kept for layout stability)
    float s = 0.0f;
    for (int mm = 0; mm < 64; ++mm) s += W3[k * 64 + mm] * W1[mm * 128 + n];
    v = s;
  } else {
    const float* srcs[10] = {W1, W2, nullptr, W3, Wu1, Wr1, Wn1, Wu2, Wr2, Wn2};
    v = srcs[m][k * Ns[m] + n];
  }
  pack[e] = bf16r(v * scl[m]);
}

__global__ __launch_bounds__(512, 2) void ode_rnn_main(
  const float* __restrict__ bts, const float* __restrict__ mtr,
  const float* __restrict__ b1, const float* __restrict__ b2, const float* __restrict__ b3,
  const float* __restrict__ bu1, const float* __restrict__ bu2,
  const float* __restrict__ br1, const float* __restrict__ br2,
  const float* __restrict__ bn1, const float* __restrict__ bn2,
  const float* __restrict__ Wu1f, const float* __restrict__ Wr1f, const float* __restrict__ Wn1f,
  const unsigned short* __restrict__ pack, float* __restrict__ out)
{
  __shared__ __align__(16) unsigned short LDSU[LDS_SHORTS];
  float* FUR = (float*)LDSU;
  const int tid = threadIdx.x, w = tid >> 6, lane = tid & 63;
  const int arow = lane & 15, g = lane >> 4, rb = g << 2;
  const int c128 = (w << 4) + arow;
  const int c64  = ((w & 3) << 4) + arow;
  const bool isMean = (w < 4);
  const int rowBase = blockIdx.x * 32;     // 32 rows per WG (two halves)

  // ---- prologue: stage shared weights into LDS ----
#pragma unroll
  for (int i = 0; i < 14; ++i){
    int idx = tid + (i << 9);
    *reinterpret_cast<bf16x8*>(LDSU + WS_O + (idx << 3)) =
        *reinterpret_cast<const bf16x8*>(pack + OFF_W3 + (idx << 3));
  }
  // zero both halves' st-mean buffers (SGH first 1024 shorts each)
  {
    int hf = tid >> 8, idx = tid & 255;
    ((unsigned long long*)(LDSU + (hf << 13) + SGH_O))[idx] = 0ULL;
  }

  // precomputed LDS indices (short units, relative to half base)
  int a128[4], wr128[4], wrmM[4], wr64[4], furi[4], a64v[2];
#pragma unroll
  for (int ks = 0; ks < 4; ++ks) a128[ks] = arow*128 + ((32*ks + 8*g) ^ (arow << 3));
#pragma unroll
  for (int ks = 0; ks < 2; ++ks) a64v[ks] = arow*64 + ((32*ks + 8*g) ^ ((arow & 7) << 3));
#pragma unroll
  for (int i = 0; i < 4; ++i){
    int r = rb + i;
    wr128[i] = r*128 + (c128 ^ (r << 3));
    wrmM[i]  = r*128 + (c64  ^ (r << 3));
    wr64[i]  = r*64  + (c64 ^ ((r & 7) << 3));
    furi[i]  = r*64 + c64;
  }
  // staged-weight bases (absolute short units, + ks<<9 per k-step)
  const int wsb  = ((4*w) << 9) + (lane << 3);
  const int w3b  = W3S  + ((4*(w & 3)) << 9) + (lane << 3);
  const int wu1b = WU1S + wsb;
  const int wr1b = WR1S + wsb;
  const int wn1b = WN1S + wsb;

  // persistent per-wave weight fragments (registers)
  bf16x8 w1f[2], w2f[4], g2wf[4], n2f[4];
#pragma unroll
  for (int ks = 0; ks < 2; ++ks) w1f[ks]  = load_bfrag(pack + OFF_W1,  2*w + ks, lane);
#pragma unroll
  for (int ks = 0; ks < 4; ++ks){
    w2f[ks]  = load_bfrag(pack + OFF_W2,  4*w + ks, lane);
    g2wf[ks] = load_bfrag(pack + (isMean ? OFF_WU2 : OFF_WR2), 4*(w & 3) + ks, lane);
    n2f[ks]  = load_bfrag(pack + OFF_WN2, 4*w + ks, lane);
  }

  const float b1c = b1[c128] * LAM, b2c = b2[c128] * LAM;
  const float b3c = b3[c64];
  const float bu1c = bu1[c128] * LAM, br1c = br1[c128] * LAM;
  const float bn1c = bn1[c128] * LAM, bn2c = bn2[c128];
  const float g2b = (isMean ? bu2[c64] : br2[c64]) * NL2E;
  const float wu1L = Wu1f[16384 + c128] * LAM, wr1L = Wr1f[16384 + c128] * LAM;
  const float wn1L = Wn1f[16384 + c128] * LAM;

  __syncthreads();   // staging + st-zero visible

  f32x4 st2[2], yf2[2], u2[2];
#pragma unroll
  for (int hf = 0; hf < 2; ++hf){
    st2[hf] = (f32x4){0.f,0.f,0.f,0.f};
    yf2[hf] = (f32x4){0.f,0.f,0.f,0.f};
    u2[hf]  = (f32x4){0.f,0.f,0.f,0.f};
  }

#pragma unroll 1
  for (int s = 0; s < T_LEN; ++s){
    const int tj = T_LEN - 1 - s;
    const float t1 = bts[2*tj];
    const float t0 = (s == 0) ? 5.0f : bts[2*tj + 2];
    const float hh = (t1 - t0);            // single Euler step per interval

    f32x4 xr2[2], mk2[2];
#pragma unroll
    for (int hf = 0; hf < 2; ++hf)
#pragma unroll
      for (int i = 0; i < 4; ++i){
        int r = rowBase + 16*hf + rb + i;
        xr2[hf][i] = bts[(r * T_LEN + tj) * 2 + 1];
        mk2[hf][i] = mtr[r * T_LEN + tj];
      }

    // ---------------- Euler: 2 phases ----------------
    // p0: h1 = tanh(st@W1+b1) (K=64 from SGH st region) -> HA
#pragma unroll
    for (int hf = 0; hf < 2; ++hf){
      unsigned short* LB = LDSU + (hf << 13);
      f32x4 acc = (f32x4){b1c, b1c, b1c, b1c};
      acc = mfma16(ldsA(LB, SGH_O + a64v[0]), w1f[0], acc);
      acc = mfma16(ldsA(LB, SGH_O + a64v[1]), w1f[1], acc);
      f32x4 h;
#pragma unroll
      for (int i = 0; i < 4; ++i) h[i] = tanh_p(acc[i]);
      packw4(LB + HA_O, wr128, h);
    }
    __syncthreads();
    // p1: h2 = tanh(h1@W2+b2); gv = hh*h2 hi/lo -> HB/SGH
#pragma unroll
    for (int hf = 0; hf < 2; ++hf){
      unsigned short* LB = LDSU + (hf << 13);
      f32x4 acc = (f32x4){b2c, b2c, b2c, b2c};
#pragma unroll
      for (int ks = 0; ks < 4; ++ks)
        acc = mfma16(ldsA(LB, HA_O + a128[ks]), w2f[ks], acc);
      f32x4 gv;
#pragma unroll
      for (int i = 0; i < 4; ++i) gv[i] = tanh_p(acc[i]) * hh;
      packw4_split(LB + HB_O, LB + SGH_O, wr128, gv);
    }
    __syncthreads();
    // Y: mean waves recover mean_ode = st + gv@W3 + hh*b3; all write state hi/lo -> HA/SGL
#pragma unroll
    for (int hf = 0; hf < 2; ++hf){
      unsigned short* LB = LDSU + (hf << 13);
      if (isMean){
        f32x4 acc = {0.f,0.f,0.f,0.f};
#pragma unroll
        for (int ks = 0; ks < 4; ++ks){
          bf16x8 wf = ldsA(LDSU, w3b + (ks << 9));
          acc = mfma16(ldsA(LB, HB_O  + a128[ks]), wf, acc);
          acc = mfma16(ldsA(LB, SGH_O + a128[ks]), wf, acc);
        }
#pragma unroll
        for (int i = 0; i < 4; ++i) yf2[hf][i] = st2[hf][i] + acc[i] + hh * b3c;
        packw4_split(LB + HA_O, LB + SGL_O, wr128, yf2[hf]);
      } else {
        packw4_split(LB + HA_O, LB + SGL_O, wr128, st2[hf]);
      }
    }
    __syncthreads();
    // g1: u & r first layers (read HA/SGL state; write au->HB, ar->SGH)
#pragma unroll
    for (int hf = 0; hf < 2; ++hf){
      unsigned short* LB = LDSU + (hf << 13);
      f32x4 au = {0.f,0.f,0.f,0.f}, ar = {0.f,0.f,0.f,0.f};
#pragma unroll
      for (int ks = 0; ks < 4; ++ks){
        bf16x8 ah = ldsA(LB, HA_O  + a128[ks]);
        bf16x8 al = ldsA(LB, SGL_O + a128[ks]);
        bf16x8 bu = ldsA(LDSU, wu1b + (ks << 9));
        bf16x8 br_ = ldsA(LDSU, wr1b + (ks << 9));
        au = mfma16(al, bu, au);  au = mfma16(ah, bu, au);
        ar = mfma16(al, br_, ar); ar = mfma16(ah, br_, ar);
      }
      f32x4 av, rv;
#pragma unroll
      for (int i = 0; i < 4; ++i){
        av[i] = tanh_p(au[i] + bu1c + xr2[hf][i] * wu1L);
        rv[i] = tanh_p(ar[i] + br1c + xr2[hf][i] * wr1L);
      }
      packw4(LB + HB_O,  wr128, av);
      packw4(LB + SGH_O, wr128, rv);
    }
    __syncthreads();
    // g2' (merged g2+g3): second layers; mean -> u (publish UX);
    // std -> rr AND both gated states yc written to HA/SGL
#pragma unroll
    for (int hf = 0; hf < 2; ++hf){
      unsigned short* LB = LDSU + (hf << 13);
      f32x4 acc = {0.f,0.f,0.f,0.f};
      const int srcO = isMean ? HB_O : SGH_O;
#pragma unroll
      for (int ks = 0; ks < 4; ++ks)
        acc = mfma16(ldsA(LB, srcO + a128[ks]), g2wf[ks], acc);
      if (isMean){
#pragma unroll
        for (int i = 0; i < 4; ++i){
          u2[hf][i] = sig_p(acc[i] + g2b);
          FUR[UX_F + (hf << 10) + furi[i]] = u2[hf][i];
        }
      } else {
        f32x4 ycm, ycs;
#pragma unroll
        for (int i = 0; i < 4; ++i){
          float rr = sig_p(acc[i] + g2b);
          float yfv = bf16tof(LB[HA_O + wrmM[i]]) + bf16tof(LB[SGL_O + wrmM[i]]);
          ycm[i] = yfv * rr;
          ycs[i] = st2[hf][i] * rr;
        }
        packw4_split(LB + HA_O, LB + SGL_O, wrmM,  ycm);
        packw4_split(LB + HA_O, LB + SGL_O, wr128, ycs);
      }
    }
    __syncthreads();
    // g4: n first layer (read HA/SGL yc; write an -> HB)
#pragma unroll
    for (int hf = 0; hf < 2; ++hf){
      unsigned short* LB = LDSU + (hf << 13);
      f32x4 an = {0.f,0.f,0.f,0.f};
#pragma unroll
      for (int ks = 0; ks < 4; ++ks){
        bf16x8 ah = ldsA(LB, HA_O  + a128[ks]);
        bf16x8 al = ldsA(LB, SGL_O + a128[ks]);
        bf16x8 bn = ldsA(LDSU, wn1b + (ks << 9));
        an = mfma16(al, bn, an); an = mfma16(ah, bn, an);
      }
      f32x4 av;
#pragma unroll
      for (int i = 0; i < 4; ++i) av[i] = tanh_p(an[i] + bn1c + xr2[hf][i] * wn1L);
      packw4(LB + HB_O, wr128, av);
    }
    __syncthreads();
    // g5: n second layer (read HB) + blend + write st-mean -> SGH st region
#pragma unroll
    for (int hf = 0; hf < 2; ++hf){
      unsigned short* LB = LDSU + (hf << 13);
      f32x4 ns = {0.f,0.f,0.f,0.f};
#pragma unroll
      for (int ks = 0; ks < 4; ++ks)
        ns = mfma16(ldsA(LB, HB_O + a128[ks]), n2f[ks], ns);
      f32x4 uu;
      if (isMean) uu = u2[hf];
      else {
#pragma unroll
        for (int i = 0; i < 4; ++i) uu[i] = FUR[UX_F + (hf << 10) + furi[i]];
      }
#pragma unroll
      for (int i = 0; i < 4; ++i){
        float nv = ns[i] + bn2c;
        float base = isMean ? yf2[hf][i] : st2[hf][i];
        float nm = (1.0f - uu[i]) * nv + uu[i] * base;
        float fs = mk2[hf][i] * nm + (1.0f - mk2[hf][i]) * base;
        st2[hf][i] = isMean ? fs : fabsf(fs);
      }
      if (isMean) packw4(LB + SGH_O, wr64, st2[hf]);
    }
    __syncthreads();
  }

  // ---------------- store ----------------
#pragma unroll
  for (int hf = 0; hf < 2; ++hf)
#pragma unroll
    for (int i = 0; i < 4; ++i){
      int r = rowBase + 16*hf + rb + i;
      if (isMean) out[r * 64 + c64] = st2[hf][i];
      else        out[524288 + r * 64 + c64] = st2[hf][i];
    }
}

extern "C" void kernel_launch(void* const* d_in, const int* in_sizes, int n_in,
                              void* d_out, int out_size, void* d_ws, size_t ws_size,
                              hipStream_t stream)
{
  (void)in_sizes; (void)n_in; (void)out_size; (void)ws_size;
  unsigned short* pack = (unsigned short*)d_ws;
  prep_pack<<<dim3((PREP_TOT + 255) / 256), dim3(256), 0, stream>>>(
      (const float*)d_in[2],  (const float*)d_in[4],  (const float*)d_in[6],
      (const float*)d_in[8],  (const float*)d_in[12], (const float*)d_in[16],
      (const float*)d_in[10], (const float*)d_in[14], (const float*)d_in[18],
      (const float*)d_in[7],  pack);
  ode_rnn_main<<<dim3(256), dim3(512), 0, stream>>>(
      (const float*)d_in[0],  (const float*)d_in[1],
      (const float*)d_in[3],  (const float*)d_in[5],  (const float*)d_in[7],
      (const float*)d_in[9],  (const float*)d_in[11],
      (const float*)d_in[13], (const float*)d_in[15],
      (const float*)d_in[17], (const float*)d_in[19],
      (const float*)d_in[8],  (const float*)d_in[12], (const float*)d_in[16],
      (const unsigned short*)pack, (float*)d_out);
}

// Round 14
// 1194.424 us; speedup vs baseline: 2.5977x; 1.0335x over previous
//
#include <hip/hip_runtime.h>

typedef __attribute__((ext_vector_type(8))) short bf16x8;
typedef __attribute__((ext_vector_type(4))) float f32x4;

#define T_LEN 256
#define LAM    2.885390081777927f    // 2*log2(e): tanh pre-scale
#define NL2E  -1.4426950408889634f   // -log2(e): sigmoid pre-scale
// pack offsets (short units)
#define OFF_W1   0
#define OFF_W2   8192
#define OFF_W3U  24576   // W3@Wu1[0:64] 128x128, LAM-scaled
#define OFF_W3   40960   // W3 128x64, unscaled
#define OFF_WU1  49152
#define OFF_WR1  65536
#define OFF_WN1  81920
#define OFF_WU2  98304
#define OFF_WR2  106496
#define OFF_WN2  114688
#define OFF_B3U  131072  // f32[128]: (b3@Wu1[0:64])*LAM  (shorts 131072..131328)
#define OFF_W3R  131328  // W3@Wr1[0:64] 128x128 bf16 frags, LAM (16384 shorts)
#define OFF_B3R  147712  // f32[128]: (b3@Wr1[0:64])*LAM
#define PREP_TOT 147712  // e-space: [0,131072) mats, [131072,131200) b3u, [131200,147584) W3R, [147584,147712) b3r

// LDS layout (short units). Two activation halves (8192 shorts each, base hf<<13),
// shared weight stage (Wu1/Wr1/Wn1), UXU u-gate floats, AR r-act buffer.
#define HA_O   0      // [16][128]: st hi / yc hi
#define HB_O   2048   // [16][128]: h1 / au / an
#define SGH_O  4096   // [16][128]: gv
#define SGL_O  6144   // [16][128]: st lo / yc lo
#define WS_O   16384  // Wu1 (16384) + Wr1 (16384) + Wn1 (16384) -> ends 65536
#define UXU_F  32768  // float idx: u gate f32 [2][1024] (shorts 65536..69631)
#define ARS    69632  // ar bf16 [2][16][128] (shorts 69632..73727)
#define LDS_SHORTS 73728

__device__ __forceinline__ float bf16tof(unsigned short u){
  unsigned int v = ((unsigned int)u) << 16;
  return __builtin_bit_cast(float, v);
}
__device__ __forceinline__ unsigned int cvt_pk_bf16(float a, float b){
  unsigned int r;
  asm("v_cvt_pk_bf16_f32 %0, %1, %2" : "=v"(r) : "v"(a), "v"(b));
  return r;
}
__device__ __forceinline__ void packw4(unsigned short* b, const int* idx, f32x4 v){
  unsigned int p0 = cvt_pk_bf16(v[0], v[1]);
  unsigned int p1 = cvt_pk_bf16(v[2], v[3]);
  b[idx[0]] = (unsigned short)p0;  b[idx[1]] = (unsigned short)(p0 >> 16);
  b[idx[2]] = (unsigned short)p1;  b[idx[3]] = (unsigned short)(p1 >> 16);
}
__device__ __forceinline__ void packw4_split(unsigned short* bh, unsigned short* bl,
                                             const int* idx, f32x4 v){
  unsigned int h0 = cvt_pk_bf16(v[0], v[1]);
  unsigned int h1 = cvt_pk_bf16(v[2], v[3]);
  float f0 = __builtin_bit_cast(float, h0 << 16);
  float f1 = __builtin_bit_cast(float, h0 & 0xffff0000u);
  float f2 = __builtin_bit_cast(float, h1 << 16);
  float f3 = __builtin_bit_cast(float, h1 & 0xffff0000u);
  unsigned int l0 = cvt_pk_bf16(v[0] - f0, v[1] - f1);
  unsigned int l1 = cvt_pk_bf16(v[2] - f2, v[3] - f3);
  bh[idx[0]] = (unsigned short)h0;  bh[idx[1]] = (unsigned short)(h0 >> 16);
  bh[idx[2]] = (unsigned short)h1;  bh[idx[3]] = (unsigned short)(h1 >> 16);
  bl[idx[0]] = (unsigned short)l0;  bl[idx[1]] = (unsigned short)(l0 >> 16);
  bl[idx[2]] = (unsigned short)l1;  bl[idx[3]] = (unsigned short)(l1 >> 16);
}
__device__ __forceinline__ float tanh_p(float x){
  return 1.0f - 2.0f * __builtin_amdgcn_rcpf(1.0f + __builtin_amdgcn_exp2f(x));
}
__device__ __forceinline__ float sig_p(float x){
  return __builtin_amdgcn_rcpf(1.0f + __builtin_amdgcn_exp2f(x));
}
__device__ __forceinline__ f32x4 mfma16(bf16x8 a, bf16x8 b, f32x4 c){
  return __builtin_amdgcn_mfma_f32_16x16x32_bf16(a, b, c, 0, 0, 0);
}
__device__ __forceinline__ bf16x8 load_bfrag(const unsigned short* p, int blk, int lane){
  return *reinterpret_cast<const bf16x8*>(p + ((blk << 6) + lane) * 8);
}
__device__ __forceinline__ bf16x8 ldsA(const unsigned short* LDSU, int idx){
  return *reinterpret_cast<const bf16x8*>(LDSU + idx);
}
__device__ __forceinline__ unsigned short bf16r(float f){
  unsigned int x = __builtin_bit_cast(unsigned int, f);
  unsigned int r = (x + 0x7FFFu + ((x >> 16) & 1u)) >> 16;
  return (unsigned short)r;
}

// Pack weights to bf16 MFMA B-fragment order with transcendental pre-scales;
// fold W3 through Wu1/Wr1: W3U=W3@Wu1[0:64] (LAM), W3R=W3@Wr1[0:64] (LAM),
// b3u=b3@Wu1[0:64] (LAM), b3r likewise.
__global__ void prep_pack(const float* __restrict__ W1, const float* __restrict__ W2,
                          const float* __restrict__ W3, const float* __restrict__ Wu1,
                          const float* __restrict__ Wr1, const float* __restrict__ Wn1,
                          const float* __restrict__ Wu2, const float* __restrict__ Wr2,
                          const float* __restrict__ Wn2, const float* __restrict__ b3,
                          unsigned short* __restrict__ pack)
{
  int e = blockIdx.x * blockDim.x + threadIdx.x;
  if (e >= PREP_TOT) return;
  if (e >= 147584){                  // b3r
    int j = e - 147584;
    float s = 0.0f;
    for (int mm = 0; mm < 64; ++mm) s += b3[mm] * Wr1[mm * 128 + j];
    ((float*)(pack + OFF_B3R))[j] = s * LAM;
    return;
  }
  if (e >= 131200){                  // W3R fragments
    int el = e - 131200;
    int j = el & 7, lane = (el >> 3) & 63, blk = el >> 9;
    int ks = blk % 4, nt = blk / 4;
    int k = ks * 32 + ((lane >> 4) << 3) + j;
    int n = nt * 16 + (lane & 15);
    float s = 0.0f;
    for (int mm = 0; mm < 64; ++mm) s += W3[k * 64 + mm] * Wr1[mm * 128 + n];
    pack[OFF_W3R + el] = bf16r(s * LAM);
    return;
  }
  if (e >= 131072){                  // b3u
    int j = e - 131072;
    float s = 0.0f;
    for (int mm = 0; mm < 64; ++mm) s += b3[mm] * Wu1[mm * 128 + j];
    ((float*)(pack + OFF_B3U))[j] = s * LAM;
    return;
  }
  const int offs[11] = {0, 8192, 24576, 40960, 49152, 65536, 81920, 98304, 106496, 114688, 131072};
  const int Ks[10] = {64,128,128,128,128,128,128,128,128,128};
  const int Ns[10] = {128,128,128,64,128,128,128,64,64,128};
  const float scl[10] = {LAM, LAM, LAM, 1.0f, LAM, LAM, LAM, NL2E, NL2E, 1.0f};
  int m = 0;
  while (e >= offs[m + 1]) ++m;
  int el = e - offs[m];
  int j = el & 7, lane = (el >> 3) & 63, blk = el >> 9;
  int ksteps = Ks[m] >> 5;
  int ks = blk % ksteps, nt = blk / ksteps;
  int k = ks * 32 + ((lane >> 4) << 3) + j;
  int n = nt * 16 + (lane & 15);
  float v;
  if (m == 2){ // W3U[k][n] = sum_mm W3[k][mm] * Wu1[mm][n]
    float s = 0.0f;
    for (int mm = 0; mm < 64; ++mm) s += W3[k * 64 + mm] * Wu1[mm * 128 + n];
    v = s;
  } else {
    const float* srcs[10] = {W1, W2, nullptr, W3, Wu1, Wr1, Wn1, Wu2, Wr2, Wn2};
    v = srcs[m][k * Ns[m] + n];
  }
  pack[e] = bf16r(v * scl[m]);
}

__global__ __launch_bounds__(512, 2) void ode_rnn_main(
  const float* __restrict__ bts, const float* __restrict__ mtr,
  const float* __restrict__ b1, const float* __restrict__ b2, const float* __restrict__ b3,
  const float* __restrict__ bu1, const float* __restrict__ bu2,
  const float* __restrict__ br1, const float* __restrict__ br2,
  const float* __restrict__ bn1, const float* __restrict__ bn2,
  const float* __restrict__ Wu1f, const float* __restrict__ Wr1f, const float* __restrict__ Wn1f,
  const unsigned short* __restrict__ pack, float* __restrict__ out)
{
  __shared__ __align__(16) unsigned short LDSU[LDS_SHORTS];
  float* FUR = (float*)LDSU;
  const int tid = threadIdx.x, w = tid >> 6, lane = tid & 63;
  const int arow = lane & 15, g = lane >> 4, rb = g << 2;
  const int c128 = (w << 4) + arow;
  const int c64  = ((w & 3) << 4) + arow;
  const bool isMean = (w < 4);
  const int rowBase = blockIdx.x * 32;     // 32 rows per WG (two halves)

  // ---- prologue: stage Wu1/Wr1/Wn1 into LDS (6144 b128 copies, 512 thr) ----
#pragma unroll
  for (int i = 0; i < 12; ++i){
    int idx = tid + (i << 9);
    *reinterpret_cast<bf16x8*>(LDSU + WS_O + (idx << 3)) =
        *reinterpret_cast<const bf16x8*>(pack + OFF_WU1 + (idx << 3));
  }
  // zero HA and SGL (st=0) for both halves
  {
    int hf = tid >> 8, idx = tid & 255;
    unsigned long long* pHA = (unsigned long long*)(LDSU + (hf << 13) + HA_O);
    unsigned long long* pSL = (unsigned long long*)(LDSU + (hf << 13) + SGL_O);
    pHA[idx] = 0ULL; pHA[idx + 256] = 0ULL;
    pSL[idx] = 0ULL; pSL[idx + 256] = 0ULL;
  }

  // precomputed LDS indices (short units, relative to half base)
  int a128[4], wr128[4], wrmM[4], furi[4];
#pragma unroll
  for (int ks = 0; ks < 4; ++ks) a128[ks] = arow*128 + ((32*ks + 8*g) ^ (arow << 3));
#pragma unroll
  for (int i = 0; i < 4; ++i){
    int r = rb + i;
    wr128[i] = r*128 + (c128 ^ (r << 3));
    wrmM[i]  = r*128 + (c64  ^ (r << 3));
    furi[i]  = r*64 + c64;
  }
  // staged-weight bases (absolute short units, + ks<<9 per k-step)
  const int wsb  = ((4*w) << 9) + (lane << 3);
  const int wu1b = WS_O + wsb;
  const int wr1b = WS_O + 16384 + wsb;
  const int wn1b = WS_O + 32768 + wsb;

  // persistent per-wave weight fragments (registers, ~104 VGPR)
  bf16x8 w1f[2], w2f[4], g2wf[4], n2f[4], w3uf[4], w3rf[4], w3f[4];
#pragma unroll
  for (int ks = 0; ks < 2; ++ks) w1f[ks]  = load_bfrag(pack + OFF_W1,  2*w + ks, lane);
#pragma unroll
  for (int ks = 0; ks < 4; ++ks){
    w2f[ks]  = load_bfrag(pack + OFF_W2,  4*w + ks, lane);
    g2wf[ks] = load_bfrag(pack + (isMean ? OFF_WU2 : OFF_WR2), 4*(w & 3) + ks, lane);
    n2f[ks]  = load_bfrag(pack + OFF_WN2, 4*w + ks, lane);
    w3uf[ks] = load_bfrag(pack + OFF_W3U, 4*w + ks, lane);
    w3rf[ks] = load_bfrag(pack + OFF_W3R, 4*w + ks, lane);
    w3f[ks]  = load_bfrag(pack + OFF_W3,  4*(w & 3) + ks, lane);
  }

  const float b1c = b1[c128] * LAM, b2c = b2[c128] * LAM;
  const float b3c = b3[c64];
  const float bu1c = bu1[c128] * LAM, br1c = br1[c128] * LAM;
  const float bn1c = bn1[c128] * LAM, bn2c = bn2[c128];
  const float g2b = (isMean ? bu2[c64] : br2[c64]) * NL2E;
  const float wu1L = Wu1f[16384 + c128] * LAM, wr1L = Wr1f[16384 + c128] * LAM;
  const float wn1L = Wn1f[16384 + c128] * LAM;
  const float b3uc = ((const float*)(pack + OFF_B3U))[c128];
  const float b3rc = ((const float*)(pack + OFF_B3R))[c128];

  __syncthreads();   // staging + st-zero visible

  f32x4 st2[2], yf2[2], u2[2];
#pragma unroll
  for (int hf = 0; hf < 2; ++hf){
    st2[hf] = (f32x4){0.f,0.f,0.f,0.f};
    yf2[hf] = (f32x4){0.f,0.f,0.f,0.f};
    u2[hf]  = (f32x4){0.f,0.f,0.f,0.f};
  }

#pragma unroll 1
  for (int s = 0; s < T_LEN; ++s){
    const int tj = T_LEN - 1 - s;
    const float t1 = bts[2*tj];
    const float t0 = (s == 0) ? 5.0f : bts[2*tj + 2];
    const float hh = (t1 - t0);            // single Euler step per interval

    f32x4 xr2[2], mk2[2];
#pragma unroll
    for (int hf = 0; hf < 2; ++hf)
#pragma unroll
      for (int i = 0; i < 4; ++i){
        int r = rowBase + 16*hf + rb + i;
        xr2[hf][i] = bts[(r * T_LEN + tj) * 2 + 1];
        mk2[hf][i] = mtr[r * T_LEN + tj];
      }

    // ---- p0: h1 = tanh(st_m@W1+b1)  (st hi, cols 0..63 of HA) -> HB ----
#pragma unroll
    for (int hf = 0; hf < 2; ++hf){
      unsigned short* LB = LDSU + (hf << 13);
      f32x4 acc = (f32x4){b1c, b1c, b1c, b1c};
      acc = mfma16(ldsA(LB, HA_O + a128[0]), w1f[0], acc);
      acc = mfma16(ldsA(LB, HA_O + a128[1]), w1f[1], acc);
      f32x4 h;
#pragma unroll
      for (int i = 0; i < 4; ++i) h[i] = tanh_p(acc[i]);
      packw4(LB + HB_O, wr128, h);
    }
    __syncthreads();
    // ---- p1: h2 = tanh(h1@W2+b2); gv = hh*h2 (single bf16) -> SGH ----
#pragma unroll
    for (int hf = 0; hf < 2; ++hf){
      unsigned short* LB = LDSU + (hf << 13);
      f32x4 acc = (f32x4){b2c, b2c, b2c, b2c};
#pragma unroll
      for (int ks = 0; ks < 4; ++ks)
        acc = mfma16(ldsA(LB, HB_O + a128[ks]), w2f[ks], acc);
      f32x4 gv;
#pragma unroll
      for (int i = 0; i < 4; ++i) gv[i] = tanh_p(acc[i]) * hh;
      packw4(LB + SGH_O, wr128, gv);
    }
    __syncthreads();
    // ---- G1 (merged Y+g1): au = tanh(st@Wu1 + gv@W3U + h*b3u + x*w + b); same r.
    //      All waves also compute their 16 cols of yf = st_m + gv@W3 + h*b3. ----
#pragma unroll
    for (int hf = 0; hf < 2; ++hf){
      unsigned short* LB = LDSU + (hf << 13);
      f32x4 au, ar;
#pragma unroll
      for (int i = 0; i < 4; ++i){
        au[i] = bu1c + hh * b3uc + xr2[hf][i] * wu1L;
        ar[i] = br1c + hh * b3rc + xr2[hf][i] * wr1L;
      }
      f32x4 ya = {0.f,0.f,0.f,0.f};
#pragma unroll
      for (int ks = 0; ks < 4; ++ks){
        bf16x8 sh = ldsA(LB, HA_O  + a128[ks]);
        bf16x8 sl = ldsA(LB, SGL_O + a128[ks]);
        bf16x8 gq = ldsA(LB, SGH_O + a128[ks]);
        bf16x8 bu = ldsA(LDSU, wu1b + (ks << 9));
        bf16x8 br_ = ldsA(LDSU, wr1b + (ks << 9));
        au = mfma16(sl, bu, au);  au = mfma16(sh, bu, au);  au = mfma16(gq, w3uf[ks], au);
        ar = mfma16(sl, br_, ar); ar = mfma16(sh, br_, ar); ar = mfma16(gq, w3rf[ks], ar);
        ya = mfma16(gq, w3f[ks], ya);
      }
      f32x4 base;
      if (isMean) base = st2[hf];
      else {
#pragma unroll
        for (int i = 0; i < 4; ++i)
          base[i] = bf16tof(LB[HA_O + wrmM[i]]) + bf16tof(LB[SGL_O + wrmM[i]]);
      }
#pragma unroll
      for (int i = 0; i < 4; ++i) yf2[hf][i] = base[i] + ya[i] + hh * b3c;
      f32x4 av, rv;
#pragma unroll
      for (int i = 0; i < 4; ++i){ av[i] = tanh_p(au[i]); rv[i] = tanh_p(ar[i]); }
      packw4(LB + HB_O, wr128, av);
      packw4(LDSU + ARS + (hf << 11), wr128, rv);
    }
    __syncthreads();
    // ---- g2': second layers; mean -> u (publish UXU); std -> rr, write yc hi/lo -> HA/SGL ----
#pragma unroll
    for (int hf = 0; hf < 2; ++hf){
      unsigned short* LB = LDSU + (hf << 13);
      f32x4 acc = {0.f,0.f,0.f,0.f};
      if (isMean){
#pragma unroll
        for (int ks = 0; ks < 4; ++ks)
          acc = mfma16(ldsA(LB, HB_O + a128[ks]), g2wf[ks], acc);
#pragma unroll
        for (int i = 0; i < 4; ++i){
          u2[hf][i] = sig_p(acc[i] + g2b);
          FUR[UXU_F + (hf << 10) + furi[i]] = u2[hf][i];
        }
      } else {
#pragma unroll
        for (int ks = 0; ks < 4; ++ks)
          acc = mfma16(ldsA(LDSU, ARS + (hf << 11) + a128[ks]), g2wf[ks], acc);
        f32x4 ycm, ycs;
#pragma unroll
        for (int i = 0; i < 4; ++i){
          float rr = sig_p(acc[i] + g2b);
          ycm[i] = yf2[hf][i] * rr;
          ycs[i] = st2[hf][i] * rr;
        }
        packw4_split(LB + HA_O, LB + SGL_O, wrmM,  ycm);
        packw4_split(LB + HA_O, LB + SGL_O, wr128, ycs);
      }
    }
    __syncthreads();
    // ---- g4: an = tanh(yc@Wn1 + x*w + b)  (read HA/SGL; write HB) ----
#pragma unroll
    for (int hf = 0; hf < 2; ++hf){
      unsigned short* LB = LDSU + (hf << 13);
      f32x4 an;
#pragma unroll
      for (int i = 0; i < 4; ++i) an[i] = bn1c + xr2[hf][i] * wn1L;
#pragma unroll
      for (int ks = 0; ks < 4; ++ks){
        bf16x8 ah = ldsA(LB, HA_O  + a128[ks]);
        bf16x8 al = ldsA(LB, SGL_O + a128[ks]);
        bf16x8 bn = ldsA(LDSU, wn1b + (ks << 9));
        an = mfma16(al, bn, an); an = mfma16(ah, bn, an);
      }
      f32x4 av;
#pragma unroll
      for (int i = 0; i < 4; ++i) av[i] = tanh_p(an[i]);
      packw4(LB + HB_O, wr128, av);
    }
    __syncthreads();
    // ---- g5: ns = an@Wn2 + b; blend; st' hi/lo -> HA/SGL ----
#pragma unroll
    for (int hf = 0; hf < 2; ++hf){
      unsigned short* LB = LDSU + (hf << 13);
      f32x4 ns = {0.f,0.f,0.f,0.f};
#pragma unroll
      for (int ks = 0; ks < 4; ++ks)
        ns = mfma16(ldsA(LB, HB_O + a128[ks]), n2f[ks], ns);
      f32x4 uu;
      if (isMean) uu = u2[hf];
      else {
#pragma unroll
        for (int i = 0; i < 4; ++i) uu[i] = FUR[UXU_F + (hf << 10) + furi[i]];
      }
#pragma unroll
      for (int i = 0; i < 4; ++i){
        float nv = ns[i] + bn2c;
        float base = isMean ? yf2[hf][i] : st2[hf][i];
        float nm = (1.0f - uu[i]) * nv + uu[i] * base;
        float fs = mk2[hf][i] * nm + (1.0f - mk2[hf][i]) * base;
        st2[hf][i] = isMean ? fs : fabsf(fs);
      }
      packw4_split(LB + HA_O, LB + SGL_O, wr128, st2[hf]);
    }
    __syncthreads();
  }

  // ---------------- store ----------------
#pragma unroll
  for (int hf = 0; hf < 2; ++hf)
#pragma unroll
    for (int i = 0; i < 4; ++i){
      int r = rowBase + 16*hf + rb + i;
      if (isMean) out[r * 64 + c64] = st2[hf][i];
      else        out[524288 + r * 64 + c64] = st2[hf][i];
    }
}

extern "C" void kernel_launch(void* const* d_in, const int* in_sizes, int n_in,
                              void* d_out, int out_size, void* d_ws, size_t ws_size,
                              hipStream_t stream)
{
  (void)in_sizes; (void)n_in; (void)out_size; (void)ws_size;
  unsigned short* pack = (unsigned short*)d_ws;
  prep_pack<<<dim3((PREP_TOT + 255) / 256), dim3(256), 0, stream>>>(
      (const float*)d_in[2],  (const float*)d_in[4],  (const float*)d_in[6],
      (const float*)d_in[8],  (const float*)d_in[12], (const float*)d_in[16],
      (const float*)d_in[10], (const float*)d_in[14], (const float*)d_in[18],
      (const float*)d_in[7],  pack);
  ode_rnn_main<<<dim3(256), dim3(512), 0, stream>>>(
      (const float*)d_in[0],  (const float*)d_in[1],
      (const float*)d_in[3],  (const float*)d_in[5],  (const float*)d_in[7],
      (const float*)d_in[9],  (const float*)d_in[11],
      (const float*)d_in[13], (const float*)d_in[15],
      (const float*)d_in[17], (const float*)d_in[19],
      (const float*)d_in[8],  (const float*)d_in[12], (const float*)d_in[16],
      (const unsigned short*)pack, (float*)d_out);
}